// Round 1
// baseline (1052.648 us; speedup 1.0000x reference)
//
#include <hip/hip_runtime.h>
#include <hip/hip_bf16.h>
#include <math.h>

#define N_NODES 20000
#define N_EDGES 320000
#define DIN 768
#define F1 1024   // H1*C1
#define H1 8
#define C1 128
#define F2 128
#define NEG_SLOPE 0.2f
#define BN_EPS 1e-5f

__device__ __forceinline__ float leaky(float x) { return x > 0.f ? x : NEG_SLOPE * x; }

// ---------------- edge_index repack (int64 or int32 -> int32) ----------------
__global__ void repack_kernel(const int* raw, int* ei32) {
  // Detect int64: for int64 input (values < 2^31), odd int32 slots are all 0.
  int is64 = (raw[1] == 0 && raw[3] == 0 && raw[5] == 0 && raw[7] == 0) ? 1 : 0;
  int e = blockIdx.x * blockDim.x + threadIdx.x;
  if (e < 2 * N_EDGES) {
    ei32[e] = is64 ? raw[2 * e] : raw[e];
  }
}

// ---------------- CSR build ----------------
__global__ void hist_kernel(const int* ei, int* deg) {
  int e = blockIdx.x * blockDim.x + threadIdx.x;
  if (e < N_EDGES) atomicAdd(&deg[ei[N_EDGES + e]], 1);
}

__global__ void scan_kernel(const int* deg, int* off, int* cursor) {
  __shared__ int tmp[1024];
  __shared__ int carry;
  if (threadIdx.x == 0) carry = 0;
  __syncthreads();
  for (int base = 0; base < N_NODES; base += 1024) {
    int i = base + threadIdx.x;
    int v = (i < N_NODES) ? deg[i] : 0;
    tmp[threadIdx.x] = v;
    __syncthreads();
    for (int s = 1; s < 1024; s <<= 1) {
      int t = (threadIdx.x >= s) ? tmp[threadIdx.x - s] : 0;
      __syncthreads();
      tmp[threadIdx.x] += t;
      __syncthreads();
    }
    int excl = tmp[threadIdx.x] - v;
    if (i < N_NODES) { int o = carry + excl; off[i] = o; cursor[i] = o; }
    __syncthreads();
    if (threadIdx.x == 1023) carry += tmp[1023];
    __syncthreads();
  }
  if (threadIdx.x == 0) off[N_NODES] = carry;
}

__global__ void scatter_kernel(const int* ei, int* cursor, int* elist) {
  int e = blockIdx.x * blockDim.x + threadIdx.x;
  if (e < N_EDGES) {
    int dst = ei[N_EDGES + e];
    int p = atomicAdd(&cursor[dst], 1);
    elist[p] = ei[e];
  }
}

// ---------------- fp32 tiled GEMM: C[M,N] = A[M,K] @ B[K,N] ----------------
#define BM 64
#define BN 64
#define BK 16
__global__ __launch_bounds__(256) void sgemm_kernel(const float* __restrict__ A,
                                                    const float* __restrict__ B,
                                                    float* __restrict__ C,
                                                    int M, int N, int K) {
  __shared__ float As[BK][BM];
  __shared__ float Bs[BK][BN];
  int tid = threadIdx.x;
  int tx = tid & 15, ty = tid >> 4;
  int row0 = blockIdx.y * BM, col0 = blockIdx.x * BN;
  float acc[4][4] = {};
  for (int k0 = 0; k0 < K; k0 += BK) {
    int ar = tid >> 2;            // 0..63
    int ak = (tid & 3) * 4;       // 0,4,8,12
    float4 av;
    if (row0 + ar < M) av = *(const float4*)(A + (size_t)(row0 + ar) * K + k0 + ak);
    else av = make_float4(0.f, 0.f, 0.f, 0.f);
    As[ak + 0][ar] = av.x; As[ak + 1][ar] = av.y;
    As[ak + 2][ar] = av.z; As[ak + 3][ar] = av.w;
    int bk = tid >> 4;            // 0..15
    int bc = (tid & 15) * 4;      // 0..60
    float4 bv = *(const float4*)(B + (size_t)(k0 + bk) * N + col0 + bc);
    *(float4*)&Bs[bk][bc] = bv;
    __syncthreads();
#pragma unroll
    for (int kk = 0; kk < BK; ++kk) {
      float4 a = *(const float4*)&As[kk][ty * 4];
      float4 b = *(const float4*)&Bs[kk][tx * 4];
      acc[0][0] += a.x * b.x; acc[0][1] += a.x * b.y; acc[0][2] += a.x * b.z; acc[0][3] += a.x * b.w;
      acc[1][0] += a.y * b.x; acc[1][1] += a.y * b.y; acc[1][2] += a.y * b.z; acc[1][3] += a.y * b.w;
      acc[2][0] += a.z * b.x; acc[2][1] += a.z * b.y; acc[2][2] += a.z * b.z; acc[2][3] += a.z * b.w;
      acc[3][0] += a.w * b.x; acc[3][1] += a.w * b.y; acc[3][2] += a.w * b.z; acc[3][3] += a.w * b.w;
    }
    __syncthreads();
  }
#pragma unroll
  for (int i = 0; i < 4; ++i) {
    int r = row0 + ty * 4 + i;
    if (r < M) {
      float4 v = make_float4(acc[i][0], acc[i][1], acc[i][2], acc[i][3]);
      *(float4*)(C + (size_t)r * N + col0 + tx * 4) = v;
    }
  }
}

// ---------------- attention logits layer 1: a_s[n,h], a_d[n,h] ----------------
__global__ void att1_kernel(const float* __restrict__ h1,
                            const float* __restrict__ att_src,
                            const float* __restrict__ att_dst,
                            float* __restrict__ as1, float* __restrict__ ad1) {
  int node = blockIdx.x;
  int tid = threadIdx.x;          // 256
  int head = tid >> 5, lane = tid & 31;
  float4 hv = *(const float4*)(h1 + (size_t)node * F1 + tid * 4);
  float4 s = *(const float4*)(att_src + head * C1 + lane * 4);
  float4 d = *(const float4*)(att_dst + head * C1 + lane * 4);
  float vs = hv.x * s.x + hv.y * s.y + hv.z * s.z + hv.w * s.w;
  float vd = hv.x * d.x + hv.y * d.y + hv.z * d.z + hv.w * d.w;
  for (int sh = 16; sh >= 1; sh >>= 1) {
    vs += __shfl_down(vs, sh, 32);
    vd += __shfl_down(vd, sh, 32);
  }
  if (lane == 0) { as1[node * H1 + head] = vs; ad1[node * H1 + head] = vd; }
}

// ---------------- gather layer 1: out1[n,1024] ----------------
__global__ __launch_bounds__(256) void gather1_kernel(const float* __restrict__ h1,
                                                      const float* __restrict__ as1,
                                                      const float* __restrict__ ad1,
                                                      const int* __restrict__ off,
                                                      const int* __restrict__ elist,
                                                      const float* __restrict__ b1,
                                                      float* __restrict__ out1) {
  int node = blockIdx.x;
  int tid = threadIdx.x;          // 256
  int head = tid >> 5;
  float ad = ad1[node * H1 + head];
  float as_self = as1[node * H1 + head];
  int s = off[node], e = off[node + 1];
  // pass 1: per-head max (incl. self loop)
  float m = leaky(as_self + ad);
  for (int i = s; i < e; ++i) {
    int src = elist[i];
    m = fmaxf(m, leaky(as1[src * H1 + head] + ad));
  }
  // pass 2: accumulate exp-weighted h rows
  float a0 = 0.f, a1 = 0.f, a2 = 0.f, a3 = 0.f, z = 0.f;
  {
    float w = __expf(leaky(as_self + ad) - m);
    z += w;
    float4 hv = *(const float4*)(h1 + (size_t)node * F1 + tid * 4);
    a0 += w * hv.x; a1 += w * hv.y; a2 += w * hv.z; a3 += w * hv.w;
  }
  for (int i = s; i < e; ++i) {
    int src = elist[i];
    float w = __expf(leaky(as1[src * H1 + head] + ad) - m);
    z += w;
    float4 hv = *(const float4*)(h1 + (size_t)src * F1 + tid * 4);
    a0 += w * hv.x; a1 += w * hv.y; a2 += w * hv.z; a3 += w * hv.w;
  }
  float inv = 1.f / z;
  float4 o = make_float4(a0 * inv + b1[tid * 4 + 0], a1 * inv + b1[tid * 4 + 1],
                         a2 * inv + b1[tid * 4 + 2], a3 * inv + b1[tid * 4 + 3]);
  *(float4*)(out1 + (size_t)node * F1 + tid * 4) = o;
}

// ---------------- BN statistics ----------------
template <int CPT>
__global__ void bnstats_kernel(const float* __restrict__ x, float* __restrict__ sums,
                               int nrows, int F, int rowsPerBlock) {
  int tid = threadIdx.x;
  int r0 = blockIdx.x * rowsPerBlock;
  int rend = min(r0 + rowsPerBlock, nrows);
  float s[CPT], q[CPT];
#pragma unroll
  for (int k = 0; k < CPT; ++k) { s[k] = 0.f; q[k] = 0.f; }
  for (int r = r0; r < rend; ++r) {
    const float* row = x + (size_t)r * F;
#pragma unroll
    for (int k = 0; k < CPT; ++k) {
      float v = row[tid + k * blockDim.x];
      s[k] += v; q[k] += v * v;
    }
  }
#pragma unroll
  for (int k = 0; k < CPT; ++k) {
    atomicAdd(&sums[tid + k * blockDim.x], s[k]);
    atomicAdd(&sums[F + tid + k * blockDim.x], q[k]);
  }
}

__global__ void bnfinal_kernel(const float* __restrict__ sums, const float* __restrict__ g,
                               const float* __restrict__ be, float* __restrict__ ss, int F) {
  int c = blockIdx.x * blockDim.x + threadIdx.x;
  if (c < F) {
    float mu = sums[c] * (1.f / N_NODES);
    float var = sums[F + c] * (1.f / N_NODES) - mu * mu;
    float sc = g[c] * rsqrtf(var + BN_EPS);
    ss[c] = sc;
    ss[F + c] = be[c] - mu * sc;
  }
}

// BN apply + ELU, in place, vectorized
__global__ void bnapply_kernel(float* __restrict__ x, const float* __restrict__ ss,
                               int F, size_t total4) {
  size_t i = (size_t)blockIdx.x * blockDim.x + threadIdx.x;
  size_t stride = (size_t)gridDim.x * blockDim.x;
  for (; i < total4; i += stride) {
    int c = (int)((i * 4) & (size_t)(F - 1));
    float4 v = ((float4*)x)[i];
    v.x = v.x * ss[c + 0] + ss[F + c + 0];
    v.y = v.y * ss[c + 1] + ss[F + c + 1];
    v.z = v.z * ss[c + 2] + ss[F + c + 2];
    v.w = v.w * ss[c + 3] + ss[F + c + 3];
    v.x = v.x > 0.f ? v.x : expm1f(v.x);
    v.y = v.y > 0.f ? v.y : expm1f(v.y);
    v.z = v.z > 0.f ? v.z : expm1f(v.z);
    v.w = v.w > 0.f ? v.w : expm1f(v.w);
    ((float4*)x)[i] = v;
  }
}

// ---------------- attention logits layer 2 ----------------
__global__ void att2_kernel(const float* __restrict__ h2,
                            const float* __restrict__ att_src,
                            const float* __restrict__ att_dst,
                            float* __restrict__ as2, float* __restrict__ ad2) {
  int node = blockIdx.x;
  int tid = threadIdx.x;          // 64
  float2 hv = *(const float2*)(h2 + (size_t)node * F2 + tid * 2);
  float2 s = *(const float2*)(att_src + tid * 2);
  float2 d = *(const float2*)(att_dst + tid * 2);
  float vs = hv.x * s.x + hv.y * s.y;
  float vd = hv.x * d.x + hv.y * d.y;
  for (int sh = 32; sh >= 1; sh >>= 1) {
    vs += __shfl_down(vs, sh, 64);
    vd += __shfl_down(vd, sh, 64);
  }
  if (tid == 0) { as2[node] = vs; ad2[node] = vd; }
}

// ---------------- gather layer 2: out2[n,128] ----------------
__global__ __launch_bounds__(128) void gather2_kernel(const float* __restrict__ h2,
                                                      const float* __restrict__ as2,
                                                      const float* __restrict__ ad2,
                                                      const int* __restrict__ off,
                                                      const int* __restrict__ elist,
                                                      const float* __restrict__ b2,
                                                      float* __restrict__ out2) {
  int node = blockIdx.x;
  int tid = threadIdx.x;          // 128
  float ad = ad2[node];
  float as_self = as2[node];
  int s = off[node], e = off[node + 1];
  float m = leaky(as_self + ad);
  for (int i = s; i < e; ++i) m = fmaxf(m, leaky(as2[elist[i]] + ad));
  float acc = 0.f, z = 0.f;
  {
    float w = __expf(leaky(as_self + ad) - m);
    z += w;
    acc += w * h2[(size_t)node * F2 + tid];
  }
  for (int i = s; i < e; ++i) {
    int src = elist[i];
    float w = __expf(leaky(as2[src] + ad) - m);
    z += w;
    acc += w * h2[(size_t)src * F2 + tid];
  }
  out2[(size_t)node * F2 + tid] = acc / z + b2[tid];
}

// ---------------- classifier head ----------------
__global__ __launch_bounds__(64) void cls_kernel(const float* __restrict__ h,
                                                 const float* __restrict__ Wc1,
                                                 const float* __restrict__ bc1,
                                                 const float* __restrict__ Wc2,
                                                 const float* __restrict__ bc2,
                                                 float* __restrict__ out) {
  __shared__ float hl[128];
  int node = blockIdx.x;
  int tid = threadIdx.x;          // 64
  hl[tid] = h[(size_t)node * F2 + tid];
  hl[tid + 64] = h[(size_t)node * F2 + 64 + tid];
  __syncthreads();
  float acc = bc1[tid];
#pragma unroll
  for (int k = 0; k < 128; ++k) acc += hl[k] * Wc1[k * 64 + tid];
  acc = fmaxf(acc, 0.f);
  float2 w = *(const float2*)(Wc2 + tid * 2);
  float o0 = acc * w.x, o1 = acc * w.y;
  for (int sh = 32; sh >= 1; sh >>= 1) {
    o0 += __shfl_down(o0, sh, 64);
    o1 += __shfl_down(o1, sh, 64);
  }
  if (tid == 0) {
    out[node * 2 + 0] = o0 + bc2[0];
    out[node * 2 + 1] = o1 + bc2[1];
  }
}

extern "C" void kernel_launch(void* const* d_in, const int* in_sizes, int n_in,
                              void* d_out, int out_size, void* d_ws, size_t ws_size,
                              hipStream_t stream) {
  const float* x        = (const float*)d_in[0];
  const int*   ei_raw   = (const int*)d_in[1];
  const float* W1       = (const float*)d_in[2];
  const float* att_src1 = (const float*)d_in[3];
  const float* att_dst1 = (const float*)d_in[4];
  const float* b1       = (const float*)d_in[5];
  const float* W2       = (const float*)d_in[6];
  const float* att_src2 = (const float*)d_in[7];
  const float* att_dst2 = (const float*)d_in[8];
  const float* b2       = (const float*)d_in[9];
  const float* g1       = (const float*)d_in[10];
  const float* be1      = (const float*)d_in[11];
  const float* g2       = (const float*)d_in[12];
  const float* be2      = (const float*)d_in[13];
  const float* Wc1      = (const float*)d_in[14];
  const float* bc1      = (const float*)d_in[15];
  const float* Wc2      = (const float*)d_in[16];
  const float* bc2      = (const float*)d_in[17];
  float* out = (float*)d_out;

  char* ws = (char*)d_ws;
  size_t o = 0;
  float* h1    = (float*)(ws + o); o += (size_t)N_NODES * F1 * 4;   // 81,920,000
  float* out1  = (float*)(ws + o); o += (size_t)N_NODES * F1 * 4;
  float* h2    = (float*)(ws + o); o += (size_t)N_NODES * F2 * 4;
  float* out2  = (float*)(ws + o); o += (size_t)N_NODES * F2 * 4;
  float* as1   = (float*)(ws + o); o += (size_t)N_NODES * H1 * 4;
  float* ad1   = (float*)(ws + o); o += (size_t)N_NODES * H1 * 4;
  float* as2   = (float*)(ws + o); o += (size_t)N_NODES * 4;
  float* ad2   = (float*)(ws + o); o += (size_t)N_NODES * 4;
  char*  zbase = ws + o;                 // contiguous zero region start
  float* bnsum1 = (float*)(ws + o); o += F1 * 2 * 4;
  float* bnsum2 = (float*)(ws + o); o += F2 * 2 * 4;
  int*   deg    = (int*)(ws + o); o += (size_t)N_NODES * 4;
  size_t zbytes = (size_t)((ws + o) - zbase);
  int*   offv   = (int*)(ws + o); o += (size_t)(N_NODES + 4) * 4;
  int*   cursor = (int*)(ws + o); o += (size_t)N_NODES * 4;
  int*   elist  = (int*)(ws + o); o += (size_t)N_EDGES * 4;
  float* ss1    = (float*)(ws + o); o += F1 * 2 * 4;
  float* ss2    = (float*)(ws + o); o += F2 * 2 * 4;
  int*   ei32   = (int*)(ws + o); o += (size_t)2 * N_EDGES * 4;
  (void)ws_size; (void)in_sizes; (void)n_in; (void)out_size;

  hipMemsetAsync((void*)zbase, 0, zbytes, stream);

  // CSR build
  repack_kernel<<<(2 * N_EDGES + 255) / 256, 256, 0, stream>>>(ei_raw, ei32);
  hist_kernel<<<(N_EDGES + 255) / 256, 256, 0, stream>>>(ei32, deg);
  scan_kernel<<<1, 1024, 0, stream>>>(deg, offv, cursor);
  scatter_kernel<<<(N_EDGES + 255) / 256, 256, 0, stream>>>(ei32, cursor, elist);

  // layer 1
  {
    dim3 grid(F1 / BN, (N_NODES + BM - 1) / BM);
    sgemm_kernel<<<grid, 256, 0, stream>>>(x, W1, h1, N_NODES, F1, DIN);
  }
  att1_kernel<<<N_NODES, 256, 0, stream>>>(h1, att_src1, att_dst1, as1, ad1);
  gather1_kernel<<<N_NODES, 256, 0, stream>>>(h1, as1, ad1, offv, elist, b1, out1);
  {
    int rows = 79;
    int grid = (N_NODES + rows - 1) / rows;
    bnstats_kernel<4><<<grid, 256, 0, stream>>>(out1, bnsum1, N_NODES, F1, rows);
  }
  bnfinal_kernel<<<(F1 + 255) / 256, 256, 0, stream>>>(bnsum1, g1, be1, ss1, F1);
  bnapply_kernel<<<2048, 256, 0, stream>>>(out1, ss1, F1, (size_t)N_NODES * F1 / 4);

  // layer 2
  {
    dim3 grid(F2 / BN, (N_NODES + BM - 1) / BM);
    sgemm_kernel<<<grid, 256, 0, stream>>>(out1, W2, h2, N_NODES, F2, F1);
  }
  att2_kernel<<<N_NODES, 64, 0, stream>>>(h2, att_src2, att_dst2, as2, ad2);
  gather2_kernel<<<N_NODES, 128, 0, stream>>>(h2, as2, ad2, offv, elist, b2, out2);
  {
    int rows = 79;
    int grid = (N_NODES + rows - 1) / rows;
    bnstats_kernel<1><<<grid, 128, 0, stream>>>(out2, bnsum2, N_NODES, F2, rows);
  }
  bnfinal_kernel<<<1, F2, 0, stream>>>(bnsum2, g2, be2, ss2, F2);
  bnapply_kernel<<<1024, 256, 0, stream>>>(out2, ss2, F2, (size_t)N_NODES * F2 / 4);

  // classifier
  cls_kernel<<<N_NODES, 64, 0, stream>>>(out2, Wc1, bc1, Wc2, bc2, out);
}

// Round 2
// 575.799 us; speedup vs baseline: 1.8282x; 1.8282x over previous
//
#include <hip/hip_runtime.h>
#include <hip/hip_bf16.h>
#include <math.h>

#define N_NODES 20000
#define N_EDGES 320000
#define DIN 768
#define F1 1024   // H1*C1
#define H1 8
#define C1 128
#define F2 128
#define NEG_SLOPE 0.2f
#define BN_EPS 1e-5f

typedef __attribute__((ext_vector_type(8))) __bf16 bf16x8;
typedef __attribute__((ext_vector_type(4))) float f32x4;

__device__ __forceinline__ float leaky(float x) { return x > 0.f ? x : NEG_SLOPE * x; }

__device__ __forceinline__ unsigned short f2bu(float x) {
  __hip_bfloat16 b = __float2bfloat16(x);
  return *(unsigned short*)&b;
}

__device__ __forceinline__ void async_copy16(void* lds, const void* g) {
  __builtin_amdgcn_global_load_lds(
      (const __attribute__((address_space(1))) unsigned int*)g,
      (__attribute__((address_space(3))) unsigned int*)lds, 16, 0, 0);
}

// ---------------- edge_index repack (int64 or int32 -> int32) ----------------
__global__ void repack_kernel(const int* raw, int* ei32) {
  int is64 = (raw[1] == 0 && raw[3] == 0 && raw[5] == 0 && raw[7] == 0) ? 1 : 0;
  int e = blockIdx.x * blockDim.x + threadIdx.x;
  if (e < 2 * N_EDGES) {
    ei32[e] = is64 ? raw[2 * e] : raw[e];
  }
}

// ---------------- CSR build ----------------
__global__ void hist_kernel(const int* ei, int* deg) {
  int e = blockIdx.x * blockDim.x + threadIdx.x;
  if (e < N_EDGES) atomicAdd(&deg[ei[N_EDGES + e]], 1);
}

__global__ void scan_kernel(const int* deg, int* off, int* cursor) {
  __shared__ int tmp[1024];
  __shared__ int carry;
  if (threadIdx.x == 0) carry = 0;
  __syncthreads();
  for (int base = 0; base < N_NODES; base += 1024) {
    int i = base + threadIdx.x;
    int v = (i < N_NODES) ? deg[i] : 0;
    tmp[threadIdx.x] = v;
    __syncthreads();
    for (int s = 1; s < 1024; s <<= 1) {
      int t = (threadIdx.x >= s) ? tmp[threadIdx.x - s] : 0;
      __syncthreads();
      tmp[threadIdx.x] += t;
      __syncthreads();
    }
    int excl = tmp[threadIdx.x] - v;
    if (i < N_NODES) { int o = carry + excl; off[i] = o; cursor[i] = o; }
    __syncthreads();
    if (threadIdx.x == 1023) carry += tmp[1023];
    __syncthreads();
  }
  if (threadIdx.x == 0) off[N_NODES] = carry;
}

__global__ void scatter_kernel(const int* ei, int* cursor, int* elist) {
  int e = blockIdx.x * blockDim.x + threadIdx.x;
  if (e < N_EDGES) {
    int dst = ei[N_EDGES + e];
    int p = atomicAdd(&cursor[dst], 1);
    elist[p] = ei[e];
  }
}

// ---------------- fp32 -> bf16 convert (float4 -> 4x bf16) ----------------
__global__ void f2b_kernel(const float* __restrict__ in, unsigned short* __restrict__ out,
                           size_t n4) {
  size_t i = (size_t)blockIdx.x * blockDim.x + threadIdx.x;
  size_t stride = (size_t)gridDim.x * blockDim.x;
  for (; i < n4; i += stride) {
    float4 v = ((const float4*)in)[i];
    ushort4 u;
    u.x = f2bu(v.x); u.y = f2bu(v.y); u.z = f2bu(v.z); u.w = f2bu(v.w);
    ((ushort4*)out)[i] = u;
  }
}

// ---------------- transpose + convert: W[K][N] fp32 -> WT[N][K] bf16 ----------------
__global__ void transpose_b_kernel(const float* __restrict__ W, unsigned short* __restrict__ WT,
                                   int K, int N) {
  __shared__ float t[32][33];
  int k0 = blockIdx.y * 32, n0 = blockIdx.x * 32;
  int tx = threadIdx.x & 31, ty = threadIdx.x >> 5;  // 256 threads, ty 0..7
  for (int i = 0; i < 32; i += 8)
    t[ty + i][tx] = W[(size_t)(k0 + ty + i) * N + n0 + tx];
  __syncthreads();
  for (int i = 0; i < 32; i += 8)
    WT[(size_t)(n0 + ty + i) * K + k0 + tx] = f2bu(t[tx][ty + i]);
}

// ---------------- bf16 MFMA GEMM: C[M,N] = A[M,K] @ BT[N,K]^T ----------------
// m97 structure: 128x128 tile, BK=64, 4 waves (2x2), global_load_lds width-16 staging.
#define GBM 128
#define GBN 128
#define GBK 64
__global__ __launch_bounds__(256) void mfma_gemm_kernel(
    const unsigned short* __restrict__ A,   // [M][K] bf16
    const unsigned short* __restrict__ BT,  // [N][K] bf16
    float* __restrict__ C,                  // [M][N] fp32
    int M, int N, int K) {
  __shared__ __hip_bfloat16 As[GBM][GBK];
  __shared__ __hip_bfloat16 Bs[GBN][GBK];
  int tid = threadIdx.x;
  int lane = tid & 63, wid = tid >> 6;
  int wr = wid >> 1, wc = wid & 1;                // 2x2 wave grid, 64x64 out each
  int row0 = blockIdx.y * GBM, col0 = blockIdx.x * GBN;
  int l16 = lane & 15, l4 = lane >> 4;
  f32x4 acc[4][4] = {};
  for (int k0 = 0; k0 < K; k0 += GBK) {
    // stage: 1024 chunks of 16B each for A and B; 256 threads x 4 iters
#pragma unroll
    for (int j = 0; j < 4; ++j) {
      int c = j * 256 + tid;
      int r = c >> 3, kk = (c & 7) << 3;
      int ga = row0 + r; if (ga >= M) ga = M - 1;
      async_copy16(&As[r][kk], A + (size_t)ga * K + k0 + kk);
      async_copy16(&Bs[r][kk], BT + (size_t)(col0 + r) * K + k0 + kk);
    }
    __syncthreads();
#pragma unroll
    for (int ks = 0; ks < 2; ++ks) {
      bf16x8 af[4], bfr[4];
#pragma unroll
      for (int i = 0; i < 4; ++i)
        af[i] = *(const bf16x8*)&As[wr * 64 + i * 16 + l16][ks * 32 + l4 * 8];
#pragma unroll
      for (int j = 0; j < 4; ++j)
        bfr[j] = *(const bf16x8*)&Bs[wc * 64 + j * 16 + l16][ks * 32 + l4 * 8];
#pragma unroll
      for (int i = 0; i < 4; ++i)
#pragma unroll
        for (int j = 0; j < 4; ++j)
          acc[i][j] = __builtin_amdgcn_mfma_f32_16x16x32_bf16(af[i], bfr[j], acc[i][j], 0, 0, 0);
    }
    __syncthreads();
  }
  // epilogue: C/D layout col=lane&15, row=(lane>>4)*4+r
#pragma unroll
  for (int i = 0; i < 4; ++i) {
#pragma unroll
    for (int j = 0; j < 4; ++j) {
#pragma unroll
      for (int r = 0; r < 4; ++r) {
        int row = row0 + wr * 64 + i * 16 + l4 * 4 + r;
        int col = col0 + wc * 64 + j * 16 + l16;
        if (row < M) C[(size_t)row * N + col] = acc[i][j][r];
      }
    }
  }
}

// ---------------- attention logits layer 1 ----------------
__global__ void att1_kernel(const float* __restrict__ h1,
                            const float* __restrict__ att_src,
                            const float* __restrict__ att_dst,
                            float* __restrict__ as1, float* __restrict__ ad1) {
  int node = blockIdx.x;
  int tid = threadIdx.x;          // 256
  int head = tid >> 5, lane = tid & 31;
  float4 hv = *(const float4*)(h1 + (size_t)node * F1 + tid * 4);
  float4 s = *(const float4*)(att_src + head * C1 + lane * 4);
  float4 d = *(const float4*)(att_dst + head * C1 + lane * 4);
  float vs = hv.x * s.x + hv.y * s.y + hv.z * s.z + hv.w * s.w;
  float vd = hv.x * d.x + hv.y * d.y + hv.z * d.z + hv.w * d.w;
  for (int sh = 16; sh >= 1; sh >>= 1) {
    vs += __shfl_down(vs, sh, 32);
    vd += __shfl_down(vd, sh, 32);
  }
  if (lane == 0) { as1[node * H1 + head] = vs; ad1[node * H1 + head] = vd; }
}

// ---------------- gather layer 1 ----------------
__global__ __launch_bounds__(256) void gather1_kernel(const float* __restrict__ h1,
                                                      const float* __restrict__ as1,
                                                      const float* __restrict__ ad1,
                                                      const int* __restrict__ off,
                                                      const int* __restrict__ elist,
                                                      const float* __restrict__ b1,
                                                      float* __restrict__ out1) {
  int node = blockIdx.x;
  int tid = threadIdx.x;          // 256
  int head = tid >> 5;
  float ad = ad1[node * H1 + head];
  float as_self = as1[node * H1 + head];
  int s = off[node], e = off[node + 1];
  float m = leaky(as_self + ad);
  for (int i = s; i < e; ++i) {
    int src = elist[i];
    m = fmaxf(m, leaky(as1[src * H1 + head] + ad));
  }
  float a0 = 0.f, a1 = 0.f, a2 = 0.f, a3 = 0.f, z = 0.f;
  {
    float w = __expf(leaky(as_self + ad) - m);
    z += w;
    float4 hv = *(const float4*)(h1 + (size_t)node * F1 + tid * 4);
    a0 += w * hv.x; a1 += w * hv.y; a2 += w * hv.z; a3 += w * hv.w;
  }
  for (int i = s; i < e; ++i) {
    int src = elist[i];
    float w = __expf(leaky(as1[src * H1 + head] + ad) - m);
    z += w;
    float4 hv = *(const float4*)(h1 + (size_t)src * F1 + tid * 4);
    a0 += w * hv.x; a1 += w * hv.y; a2 += w * hv.z; a3 += w * hv.w;
  }
  float inv = 1.f / z;
  float4 o = make_float4(a0 * inv + b1[tid * 4 + 0], a1 * inv + b1[tid * 4 + 1],
                         a2 * inv + b1[tid * 4 + 2], a3 * inv + b1[tid * 4 + 3]);
  *(float4*)(out1 + (size_t)node * F1 + tid * 4) = o;
}

// ---------------- BN statistics ----------------
template <int CPT>
__global__ void bnstats_kernel(const float* __restrict__ x, float* __restrict__ sums,
                               int nrows, int F, int rowsPerBlock) {
  int tid = threadIdx.x;
  int r0 = blockIdx.x * rowsPerBlock;
  int rend = min(r0 + rowsPerBlock, nrows);
  float s[CPT], q[CPT];
#pragma unroll
  for (int k = 0; k < CPT; ++k) { s[k] = 0.f; q[k] = 0.f; }
  for (int r = r0; r < rend; ++r) {
    const float* row = x + (size_t)r * F;
#pragma unroll
    for (int k = 0; k < CPT; ++k) {
      float v = row[tid + k * blockDim.x];
      s[k] += v; q[k] += v * v;
    }
  }
#pragma unroll
  for (int k = 0; k < CPT; ++k) {
    atomicAdd(&sums[tid + k * blockDim.x], s[k]);
    atomicAdd(&sums[F + tid + k * blockDim.x], q[k]);
  }
}

__global__ void bnfinal_kernel(const float* __restrict__ sums, const float* __restrict__ g,
                               const float* __restrict__ be, float* __restrict__ ss, int F) {
  int c = blockIdx.x * blockDim.x + threadIdx.x;
  if (c < F) {
    float mu = sums[c] * (1.f / N_NODES);
    float var = sums[F + c] * (1.f / N_NODES) - mu * mu;
    float sc = g[c] * rsqrtf(var + BN_EPS);
    ss[c] = sc;
    ss[F + c] = be[c] - mu * sc;
  }
}

// BN apply + ELU, fp32 in-place (layer 2)
__global__ void bnapply_kernel(float* __restrict__ x, const float* __restrict__ ss,
                               int F, size_t total4) {
  size_t i = (size_t)blockIdx.x * blockDim.x + threadIdx.x;
  size_t stride = (size_t)gridDim.x * blockDim.x;
  for (; i < total4; i += stride) {
    int c = (int)((i * 4) & (size_t)(F - 1));
    float4 v = ((float4*)x)[i];
    v.x = v.x * ss[c + 0] + ss[F + c + 0];
    v.y = v.y * ss[c + 1] + ss[F + c + 1];
    v.z = v.z * ss[c + 2] + ss[F + c + 2];
    v.w = v.w * ss[c + 3] + ss[F + c + 3];
    v.x = v.x > 0.f ? v.x : expm1f(v.x);
    v.y = v.y > 0.f ? v.y : expm1f(v.y);
    v.z = v.z > 0.f ? v.z : expm1f(v.z);
    v.w = v.w > 0.f ? v.w : expm1f(v.w);
    ((float4*)x)[i] = v;
  }
}

// BN apply + ELU, fp32 in -> bf16 out (layer 1, feeds GEMM2)
__global__ void bnapply_bf16_kernel(const float* __restrict__ x, const float* __restrict__ ss,
                                    unsigned short* __restrict__ y, int F, size_t total4) {
  size_t i = (size_t)blockIdx.x * blockDim.x + threadIdx.x;
  size_t stride = (size_t)gridDim.x * blockDim.x;
  for (; i < total4; i += stride) {
    int c = (int)((i * 4) & (size_t)(F - 1));
    float4 v = ((const float4*)x)[i];
    v.x = v.x * ss[c + 0] + ss[F + c + 0];
    v.y = v.y * ss[c + 1] + ss[F + c + 1];
    v.z = v.z * ss[c + 2] + ss[F + c + 2];
    v.w = v.w * ss[c + 3] + ss[F + c + 3];
    v.x = v.x > 0.f ? v.x : expm1f(v.x);
    v.y = v.y > 0.f ? v.y : expm1f(v.y);
    v.z = v.z > 0.f ? v.z : expm1f(v.z);
    v.w = v.w > 0.f ? v.w : expm1f(v.w);
    ushort4 u;
    u.x = f2bu(v.x); u.y = f2bu(v.y); u.z = f2bu(v.z); u.w = f2bu(v.w);
    ((ushort4*)y)[i] = u;
  }
}

// ---------------- attention logits layer 2 ----------------
__global__ void att2_kernel(const float* __restrict__ h2,
                            const float* __restrict__ att_src,
                            const float* __restrict__ att_dst,
                            float* __restrict__ as2, float* __restrict__ ad2) {
  int node = blockIdx.x;
  int tid = threadIdx.x;          // 64
  float2 hv = *(const float2*)(h2 + (size_t)node * F2 + tid * 2);
  float2 s = *(const float2*)(att_src + tid * 2);
  float2 d = *(const float2*)(att_dst + tid * 2);
  float vs = hv.x * s.x + hv.y * s.y;
  float vd = hv.x * d.x + hv.y * d.y;
  for (int sh = 32; sh >= 1; sh >>= 1) {
    vs += __shfl_down(vs, sh, 64);
    vd += __shfl_down(vd, sh, 64);
  }
  if (tid == 0) { as2[node] = vs; ad2[node] = vd; }
}

// ---------------- gather layer 2 ----------------
__global__ __launch_bounds__(128) void gather2_kernel(const float* __restrict__ h2,
                                                      const float* __restrict__ as2,
                                                      const float* __restrict__ ad2,
                                                      const int* __restrict__ off,
                                                      const int* __restrict__ elist,
                                                      const float* __restrict__ b2,
                                                      float* __restrict__ out2) {
  int node = blockIdx.x;
  int tid = threadIdx.x;          // 128
  float ad = ad2[node];
  float as_self = as2[node];
  int s = off[node], e = off[node + 1];
  float m = leaky(as_self + ad);
  for (int i = s; i < e; ++i) m = fmaxf(m, leaky(as2[elist[i]] + ad));
  float acc = 0.f, z = 0.f;
  {
    float w = __expf(leaky(as_self + ad) - m);
    z += w;
    acc += w * h2[(size_t)node * F2 + tid];
  }
  for (int i = s; i < e; ++i) {
    int src = elist[i];
    float w = __expf(leaky(as2[src] + ad) - m);
    z += w;
    acc += w * h2[(size_t)src * F2 + tid];
  }
  out2[(size_t)node * F2 + tid] = acc / z + b2[tid];
}

// ---------------- classifier head ----------------
__global__ __launch_bounds__(64) void cls_kernel(const float* __restrict__ h,
                                                 const float* __restrict__ Wc1,
                                                 const float* __restrict__ bc1,
                                                 const float* __restrict__ Wc2,
                                                 const float* __restrict__ bc2,
                                                 float* __restrict__ out) {
  __shared__ float hl[128];
  int node = blockIdx.x;
  int tid = threadIdx.x;          // 64
  hl[tid] = h[(size_t)node * F2 + tid];
  hl[tid + 64] = h[(size_t)node * F2 + 64 + tid];
  __syncthreads();
  float acc = bc1[tid];
#pragma unroll
  for (int k = 0; k < 128; ++k) acc += hl[k] * Wc1[k * 64 + tid];
  acc = fmaxf(acc, 0.f);
  float2 w = *(const float2*)(Wc2 + tid * 2);
  float o0 = acc * w.x, o1 = acc * w.y;
  for (int sh = 32; sh >= 1; sh >>= 1) {
    o0 += __shfl_down(o0, sh, 64);
    o1 += __shfl_down(o1, sh, 64);
  }
  if (tid == 0) {
    out[node * 2 + 0] = o0 + bc2[0];
    out[node * 2 + 1] = o1 + bc2[1];
  }
}

extern "C" void kernel_launch(void* const* d_in, const int* in_sizes, int n_in,
                              void* d_out, int out_size, void* d_ws, size_t ws_size,
                              hipStream_t stream) {
  const float* x        = (const float*)d_in[0];
  const int*   ei_raw   = (const int*)d_in[1];
  const float* W1       = (const float*)d_in[2];
  const float* att_src1 = (const float*)d_in[3];
  const float* att_dst1 = (const float*)d_in[4];
  const float* b1       = (const float*)d_in[5];
  const float* W2       = (const float*)d_in[6];
  const float* att_src2 = (const float*)d_in[7];
  const float* att_dst2 = (const float*)d_in[8];
  const float* b2       = (const float*)d_in[9];
  const float* g1       = (const float*)d_in[10];
  const float* be1      = (const float*)d_in[11];
  const float* g2       = (const float*)d_in[12];
  const float* be2      = (const float*)d_in[13];
  const float* Wc1      = (const float*)d_in[14];
  const float* bc1      = (const float*)d_in[15];
  const float* Wc2      = (const float*)d_in[16];
  const float* bc2      = (const float*)d_in[17];
  float* out = (float*)d_out;

  char* ws = (char*)d_ws;
  size_t o = 0;
  float* h1    = (float*)(ws + o); o += (size_t)N_NODES * F1 * 4;   // 81.92 MB
  float* out1  = (float*)(ws + o); o += (size_t)N_NODES * F1 * 4;   // 81.92 MB
  float* h2    = (float*)(ws + o); o += (size_t)N_NODES * F2 * 4;
  float* out2  = (float*)(ws + o); o += (size_t)N_NODES * F2 * 4;
  float* as1   = (float*)(ws + o); o += (size_t)N_NODES * H1 * 4;
  float* ad1   = (float*)(ws + o); o += (size_t)N_NODES * H1 * 4;
  float* as2   = (float*)(ws + o); o += (size_t)N_NODES * 4;
  float* ad2   = (float*)(ws + o); o += (size_t)N_NODES * 4;
  char*  zbase = ws + o;
  float* bnsum1 = (float*)(ws + o); o += F1 * 2 * 4;
  float* bnsum2 = (float*)(ws + o); o += F2 * 2 * 4;
  int*   deg    = (int*)(ws + o); o += (size_t)N_NODES * 4;
  size_t zbytes = (size_t)((ws + o) - zbase);
  int*   offv   = (int*)(ws + o); o += (size_t)(N_NODES + 4) * 4;
  int*   cursor = (int*)(ws + o); o += (size_t)N_NODES * 4;
  int*   elist  = (int*)(ws + o); o += (size_t)N_EDGES * 4;
  float* ss1    = (float*)(ws + o); o += F1 * 2 * 4;
  float* ss2    = (float*)(ws + o); o += F2 * 2 * 4;
  int*   ei32   = (int*)(ws + o); o += (size_t)2 * N_EDGES * 4;
  unsigned short* W1T = (unsigned short*)(ws + o); o += (size_t)F1 * DIN * 2;   // 1.54 MB
  unsigned short* W2T = (unsigned short*)(ws + o); o += (size_t)F2 * F1 * 2;    // 0.26 MB
  // aliases (sequential lifetimes):
  unsigned short* xb    = (unsigned short*)out1;  // x bf16 [20000][768]; dead before gather1 writes out1
  unsigned short* out1b = (unsigned short*)h1;    // BN+ELU bf16 [20000][1024]; written after h1 is dead
  (void)ws_size; (void)in_sizes; (void)n_in; (void)out_size;

  hipMemsetAsync((void*)zbase, 0, zbytes, stream);

  // input conversions
  f2b_kernel<<<2048, 256, 0, stream>>>(x, xb, (size_t)N_NODES * DIN / 4);
  {
    dim3 g1d(F1 / 32, DIN / 32);
    transpose_b_kernel<<<g1d, 256, 0, stream>>>(W1, W1T, DIN, F1);
    dim3 g2d(F2 / 32, F1 / 32);
    transpose_b_kernel<<<g2d, 256, 0, stream>>>(W2, W2T, F1, F2);
  }

  // CSR build
  repack_kernel<<<(2 * N_EDGES + 255) / 256, 256, 0, stream>>>(ei_raw, ei32);
  hist_kernel<<<(N_EDGES + 255) / 256, 256, 0, stream>>>(ei32, deg);
  scan_kernel<<<1, 1024, 0, stream>>>(deg, offv, cursor);
  scatter_kernel<<<(N_EDGES + 255) / 256, 256, 0, stream>>>(ei32, cursor, elist);

  // layer 1: h1 = x @ W1  (bf16 MFMA)
  {
    dim3 grid(F1 / GBN, (N_NODES + GBM - 1) / GBM);
    mfma_gemm_kernel<<<grid, 256, 0, stream>>>(xb, W1T, h1, N_NODES, F1, DIN);
  }
  att1_kernel<<<N_NODES, 256, 0, stream>>>(h1, att_src1, att_dst1, as1, ad1);
  gather1_kernel<<<N_NODES, 256, 0, stream>>>(h1, as1, ad1, offv, elist, b1, out1);
  {
    int rows = 79;
    int grid = (N_NODES + rows - 1) / rows;
    bnstats_kernel<4><<<grid, 256, 0, stream>>>(out1, bnsum1, N_NODES, F1, rows);
  }
  bnfinal_kernel<<<(F1 + 255) / 256, 256, 0, stream>>>(bnsum1, g1, be1, ss1, F1);
  bnapply_bf16_kernel<<<2048, 256, 0, stream>>>(out1, ss1, out1b, F1, (size_t)N_NODES * F1 / 4);

  // layer 2: h2 = out1b @ W2  (bf16 MFMA)
  {
    dim3 grid(F2 / GBN, (N_NODES + GBM - 1) / GBM);
    mfma_gemm_kernel<<<grid, 256, 0, stream>>>(out1b, W2T, h2, N_NODES, F2, F1);
  }
  att2_kernel<<<N_NODES, 64, 0, stream>>>(h2, att_src2, att_dst2, as2, ad2);
  gather2_kernel<<<N_NODES, 128, 0, stream>>>(h2, as2, ad2, offv, elist, b2, out2);
  {
    int rows = 79;
    int grid = (N_NODES + rows - 1) / rows;
    bnstats_kernel<1><<<grid, 128, 0, stream>>>(out2, bnsum2, N_NODES, F2, rows);
  }
  bnfinal_kernel<<<1, F2, 0, stream>>>(bnsum2, g2, be2, ss2, F2);
  bnapply_kernel<<<1024, 256, 0, stream>>>(out2, ss2, F2, (size_t)N_NODES * F2 / 4);

  // classifier
  cls_kernel<<<N_NODES, 64, 0, stream>>>(out2, Wc1, bc1, Wc2, bc2, out);
}

// Round 3
// 495.696 us; speedup vs baseline: 2.1236x; 1.1616x over previous
//
#include <hip/hip_runtime.h>
#include <hip/hip_bf16.h>
#include <math.h>

#define N_NODES 20000
#define N_EDGES 320000
#define DIN 768
#define F1 1024   // H1*C1
#define H1 8
#define C1 128
#define F2 128
#define NEG_SLOPE 0.2f
#define BN_EPS 1e-5f

typedef __attribute__((ext_vector_type(8))) __bf16 bf16x8;
typedef __attribute__((ext_vector_type(4))) float f32x4;

__device__ __forceinline__ float leaky(float x) { return x > 0.f ? x : NEG_SLOPE * x; }

__device__ __forceinline__ unsigned short f2bu(float x) {
  __hip_bfloat16 b = __float2bfloat16(x);
  return *(unsigned short*)&b;
}
__device__ __forceinline__ float b2f(unsigned short u) {
  return __uint_as_float(((unsigned)u) << 16);
}

__device__ __forceinline__ void async_copy16(void* lds, const void* g) {
  __builtin_amdgcn_global_load_lds(
      (const __attribute__((address_space(1))) unsigned int*)g,
      (__attribute__((address_space(3))) unsigned int*)lds, 16, 0, 0);
}

// ---------------- edge_index repack (int64 or int32 -> int32) ----------------
__global__ void repack_kernel(const int* raw, int* ei32) {
  int is64 = (raw[1] == 0 && raw[3] == 0 && raw[5] == 0 && raw[7] == 0) ? 1 : 0;
  int e = blockIdx.x * blockDim.x + threadIdx.x;
  if (e < 2 * N_EDGES) {
    ei32[e] = is64 ? raw[2 * e] : raw[e];
  }
}

// ---------------- CSR build ----------------
__global__ void hist_kernel(const int* ei, int* deg) {
  int e = blockIdx.x * blockDim.x + threadIdx.x;
  if (e < N_EDGES) atomicAdd(&deg[ei[N_EDGES + e]], 1);
}

__global__ void scan_kernel(const int* deg, int* off, int* cursor) {
  __shared__ int tmp[1024];
  __shared__ int carry;
  if (threadIdx.x == 0) carry = 0;
  __syncthreads();
  for (int base = 0; base < N_NODES; base += 1024) {
    int i = base + threadIdx.x;
    int v = (i < N_NODES) ? deg[i] : 0;
    tmp[threadIdx.x] = v;
    __syncthreads();
    for (int s = 1; s < 1024; s <<= 1) {
      int t = (threadIdx.x >= s) ? tmp[threadIdx.x - s] : 0;
      __syncthreads();
      tmp[threadIdx.x] += t;
      __syncthreads();
    }
    int excl = tmp[threadIdx.x] - v;
    if (i < N_NODES) { int o = carry + excl; off[i] = o; cursor[i] = o; }
    __syncthreads();
    if (threadIdx.x == 1023) carry += tmp[1023];
    __syncthreads();
  }
  if (threadIdx.x == 0) off[N_NODES] = carry;
}

__global__ void scatter_kernel(const int* ei, int* cursor, int* elist) {
  int e = blockIdx.x * blockDim.x + threadIdx.x;
  if (e < N_EDGES) {
    int dst = ei[N_EDGES + e];
    int p = atomicAdd(&cursor[dst], 1);
    elist[p] = ei[e];
  }
}

// ---------------- fp32 -> bf16 convert ----------------
__global__ void f2b_kernel(const float* __restrict__ in, unsigned short* __restrict__ out,
                           size_t n4) {
  size_t i = (size_t)blockIdx.x * blockDim.x + threadIdx.x;
  size_t stride = (size_t)gridDim.x * blockDim.x;
  for (; i < n4; i += stride) {
    float4 v = ((const float4*)in)[i];
    ushort4 u;
    u.x = f2bu(v.x); u.y = f2bu(v.y); u.z = f2bu(v.z); u.w = f2bu(v.w);
    ((ushort4*)out)[i] = u;
  }
}

// ---------------- transpose + convert: W[K][N] fp32 -> WT[N][K] bf16 ----------------
__global__ void transpose_b_kernel(const float* __restrict__ W, unsigned short* __restrict__ WT,
                                   int K, int N) {
  __shared__ float t[32][33];
  int k0 = blockIdx.y * 32, n0 = blockIdx.x * 32;
  int tx = threadIdx.x & 31, ty = threadIdx.x >> 5;
  for (int i = 0; i < 32; i += 8)
    t[ty + i][tx] = W[(size_t)(k0 + ty + i) * N + n0 + tx];
  __syncthreads();
  for (int i = 0; i < 32; i += 8)
    WT[(size_t)(n0 + ty + i) * K + k0 + tx] = f2bu(t[tx][ty + i]);
}

// ---------------- bf16 MFMA GEMM + fused att-logit epilogue ----------------
// C[M,N] = A[M,K] @ BT[N,K]^T, C stored bf16. Each 128-col tile == one head
// (C==128), so the epilogue computes as/ad for its head from fp32 accums.
#define GBM 128
#define GBN 128
#define GBK 64
template <int H>
__global__ __launch_bounds__(256) void mfma_gemm_att_kernel(
    const unsigned short* __restrict__ A,   // [M][K] bf16
    const unsigned short* __restrict__ BT,  // [N][K] bf16
    unsigned short* __restrict__ C,         // [M][N] bf16
    const float* __restrict__ att_src,      // [N] (== [H][128])
    const float* __restrict__ att_dst,      // [N]
    float* __restrict__ as_out,             // [M][H]
    float* __restrict__ ad_out,             // [M][H]
    int M, int N, int K) {
  __shared__ __hip_bfloat16 As[GBM][GBK];
  __shared__ __hip_bfloat16 Bs[GBN][GBK];
  __shared__ float sred[128][2];
  __shared__ float dred[128][2];
  int tid = threadIdx.x;
  int lane = tid & 63, wid = tid >> 6;
  int wr = wid >> 1, wc = wid & 1;                // 2x2 wave grid, 64x64 out each
  int row0 = blockIdx.y * GBM, col0 = blockIdx.x * GBN;
  int head = blockIdx.x;                          // gridDim.x == H
  int l16 = lane & 15, l4 = lane >> 4;
  f32x4 acc[4][4] = {};
  for (int k0 = 0; k0 < K; k0 += GBK) {
#pragma unroll
    for (int j = 0; j < 4; ++j) {
      int c = j * 256 + tid;
      int r = c >> 3, kk = (c & 7) << 3;
      int ga = row0 + r; if (ga >= M) ga = M - 1;
      async_copy16(&As[r][kk], A + (size_t)ga * K + k0 + kk);
      async_copy16(&Bs[r][kk], BT + (size_t)(col0 + r) * K + k0 + kk);
    }
    __syncthreads();
#pragma unroll
    for (int ks = 0; ks < 2; ++ks) {
      bf16x8 af[4], bfr[4];
#pragma unroll
      for (int i = 0; i < 4; ++i)
        af[i] = *(const bf16x8*)&As[wr * 64 + i * 16 + l16][ks * 32 + l4 * 8];
#pragma unroll
      for (int j = 0; j < 4; ++j)
        bfr[j] = *(const bf16x8*)&Bs[wc * 64 + j * 16 + l16][ks * 32 + l4 * 8];
#pragma unroll
      for (int i = 0; i < 4; ++i)
#pragma unroll
        for (int j = 0; j < 4; ++j)
          acc[i][j] = __builtin_amdgcn_mfma_f32_16x16x32_bf16(af[i], bfr[j], acc[i][j], 0, 0, 0);
    }
    __syncthreads();
  }
  // ---- C store (bf16): col=lane&15, row=(lane>>4)*4+r ----
#pragma unroll
  for (int i = 0; i < 4; ++i) {
#pragma unroll
    for (int j = 0; j < 4; ++j) {
#pragma unroll
      for (int r = 0; r < 4; ++r) {
        int row = row0 + wr * 64 + i * 16 + l4 * 4 + r;
        int col = col0 + wc * 64 + j * 16 + l16;
        if (row < M) C[(size_t)row * N + col] = f2bu(acc[i][j][r]);
      }
    }
  }
  // ---- fused attention logits from fp32 accumulators ----
  float avs[4], avd[4];
#pragma unroll
  for (int j = 0; j < 4; ++j) {
    int col = col0 + wc * 64 + j * 16 + l16;
    avs[j] = att_src[col];
    avd[j] = att_dst[col];
  }
#pragma unroll
  for (int i = 0; i < 4; ++i) {
#pragma unroll
    for (int r = 0; r < 4; ++r) {
      float ps = 0.f, pd = 0.f;
#pragma unroll
      for (int j = 0; j < 4; ++j) { ps += acc[i][j][r] * avs[j]; pd += acc[i][j][r] * avd[j]; }
#pragma unroll
      for (int mk = 1; mk < 16; mk <<= 1) {
        ps += __shfl_xor(ps, mk, 64);
        pd += __shfl_xor(pd, mk, 64);
      }
      if (l16 == 0) {
        int lr = wr * 64 + i * 16 + l4 * 4 + r;
        sred[lr][wc] = ps;
        dred[lr][wc] = pd;
      }
    }
  }
  __syncthreads();
  if (tid < 128) {
    int row = row0 + tid;
    if (row < M) {
      as_out[(size_t)row * H + head] = sred[tid][0] + sred[tid][1];
      ad_out[(size_t)row * H + head] = dred[tid][0] + dred[tid][1];
    }
  }
}

// ---------------- gather layer 1 (bf16 rows, fp32 accum, bf16 out) ----------------
__global__ __launch_bounds__(256) void gather1_kernel(const unsigned short* __restrict__ h1,
                                                      const float* __restrict__ as1,
                                                      const float* __restrict__ ad1,
                                                      const int* __restrict__ off,
                                                      const int* __restrict__ elist,
                                                      const float* __restrict__ b1,
                                                      unsigned short* __restrict__ out1) {
  int node = blockIdx.x;
  int tid = threadIdx.x;          // 256, 4 channels each
  int head = tid >> 5;
  float ad = ad1[node * H1 + head];
  float as_self = as1[node * H1 + head];
  int s = off[node], e = off[node + 1];
  float m = leaky(as_self + ad);
  for (int i = s; i < e; ++i) {
    int src = elist[i];
    m = fmaxf(m, leaky(as1[src * H1 + head] + ad));
  }
  float a0 = 0.f, a1 = 0.f, a2 = 0.f, a3 = 0.f, z = 0.f;
  {
    float w = __expf(leaky(as_self + ad) - m);
    z += w;
    ushort4 hv = *(const ushort4*)(h1 + (size_t)node * F1 + tid * 4);
    a0 += w * b2f(hv.x); a1 += w * b2f(hv.y); a2 += w * b2f(hv.z); a3 += w * b2f(hv.w);
  }
  for (int i = s; i < e; ++i) {
    int src = elist[i];
    float w = __expf(leaky(as1[src * H1 + head] + ad) - m);
    z += w;
    ushort4 hv = *(const ushort4*)(h1 + (size_t)src * F1 + tid * 4);
    a0 += w * b2f(hv.x); a1 += w * b2f(hv.y); a2 += w * b2f(hv.z); a3 += w * b2f(hv.w);
  }
  float inv = 1.f / z;
  ushort4 o;
  o.x = f2bu(a0 * inv + b1[tid * 4 + 0]);
  o.y = f2bu(a1 * inv + b1[tid * 4 + 1]);
  o.z = f2bu(a2 * inv + b1[tid * 4 + 2]);
  o.w = f2bu(a3 * inv + b1[tid * 4 + 3]);
  *(ushort4*)(out1 + (size_t)node * F1 + tid * 4) = o;
}

// ---------------- BN statistics, bf16 input ----------------
__global__ void bnstats_bf16_kernel(const unsigned short* __restrict__ x,
                                    float* __restrict__ sums,
                                    int nrows, int F, int rowsPerBlock) {
  int tid = threadIdx.x;          // F/4 threads, 4 contiguous channels each
  int c = tid * 4;
  int r0 = blockIdx.x * rowsPerBlock;
  int rend = min(r0 + rowsPerBlock, nrows);
  float s0 = 0.f, s1 = 0.f, s2 = 0.f, s3 = 0.f;
  float q0 = 0.f, q1 = 0.f, q2 = 0.f, q3 = 0.f;
  for (int r = r0; r < rend; ++r) {
    ushort4 u = *(const ushort4*)(x + (size_t)r * F + c);
    float v0 = b2f(u.x), v1 = b2f(u.y), v2 = b2f(u.z), v3 = b2f(u.w);
    s0 += v0; s1 += v1; s2 += v2; s3 += v3;
    q0 += v0 * v0; q1 += v1 * v1; q2 += v2 * v2; q3 += v3 * v3;
  }
  atomicAdd(&sums[c + 0], s0); atomicAdd(&sums[c + 1], s1);
  atomicAdd(&sums[c + 2], s2); atomicAdd(&sums[c + 3], s3);
  atomicAdd(&sums[F + c + 0], q0); atomicAdd(&sums[F + c + 1], q1);
  atomicAdd(&sums[F + c + 2], q2); atomicAdd(&sums[F + c + 3], q3);
}

// fp32-input variant (layer 2, small)
template <int CPT>
__global__ void bnstats_kernel(const float* __restrict__ x, float* __restrict__ sums,
                               int nrows, int F, int rowsPerBlock) {
  int tid = threadIdx.x;
  int r0 = blockIdx.x * rowsPerBlock;
  int rend = min(r0 + rowsPerBlock, nrows);
  float s[CPT], q[CPT];
#pragma unroll
  for (int k = 0; k < CPT; ++k) { s[k] = 0.f; q[k] = 0.f; }
  for (int r = r0; r < rend; ++r) {
    const float* row = x + (size_t)r * F;
#pragma unroll
    for (int k = 0; k < CPT; ++k) {
      float v = row[tid + k * blockDim.x];
      s[k] += v; q[k] += v * v;
    }
  }
#pragma unroll
  for (int k = 0; k < CPT; ++k) {
    atomicAdd(&sums[tid + k * blockDim.x], s[k]);
    atomicAdd(&sums[F + tid + k * blockDim.x], q[k]);
  }
}

__global__ void bnfinal_kernel(const float* __restrict__ sums, const float* __restrict__ g,
                               const float* __restrict__ be, float* __restrict__ ss, int F) {
  int c = blockIdx.x * blockDim.x + threadIdx.x;
  if (c < F) {
    float mu = sums[c] * (1.f / N_NODES);
    float var = sums[F + c] * (1.f / N_NODES) - mu * mu;
    float sc = g[c] * rsqrtf(var + BN_EPS);
    ss[c] = sc;
    ss[F + c] = be[c] - mu * sc;
  }
}

// BN apply + ELU, bf16 in-place (layer 1, feeds GEMM2)
__global__ void bnapply_bf16_kernel(unsigned short* __restrict__ x, const float* __restrict__ ss,
                                    int F, size_t total4) {
  size_t i = (size_t)blockIdx.x * blockDim.x + threadIdx.x;
  size_t stride = (size_t)gridDim.x * blockDim.x;
  for (; i < total4; i += stride) {
    int c = (int)((i * 4) & (size_t)(F - 1));
    ushort4 u = ((ushort4*)x)[i];
    float v0 = b2f(u.x) * ss[c + 0] + ss[F + c + 0];
    float v1 = b2f(u.y) * ss[c + 1] + ss[F + c + 1];
    float v2 = b2f(u.z) * ss[c + 2] + ss[F + c + 2];
    float v3 = b2f(u.w) * ss[c + 3] + ss[F + c + 3];
    v0 = v0 > 0.f ? v0 : expm1f(v0);
    v1 = v1 > 0.f ? v1 : expm1f(v1);
    v2 = v2 > 0.f ? v2 : expm1f(v2);
    v3 = v3 > 0.f ? v3 : expm1f(v3);
    u.x = f2bu(v0); u.y = f2bu(v1); u.z = f2bu(v2); u.w = f2bu(v3);
    ((ushort4*)x)[i] = u;
  }
}

// BN apply + ELU, fp32 in-place (layer 2)
__global__ void bnapply_kernel(float* __restrict__ x, const float* __restrict__ ss,
                               int F, size_t total4) {
  size_t i = (size_t)blockIdx.x * blockDim.x + threadIdx.x;
  size_t stride = (size_t)gridDim.x * blockDim.x;
  for (; i < total4; i += stride) {
    int c = (int)((i * 4) & (size_t)(F - 1));
    float4 v = ((float4*)x)[i];
    v.x = v.x * ss[c + 0] + ss[F + c + 0];
    v.y = v.y * ss[c + 1] + ss[F + c + 1];
    v.z = v.z * ss[c + 2] + ss[F + c + 2];
    v.w = v.w * ss[c + 3] + ss[F + c + 3];
    v.x = v.x > 0.f ? v.x : expm1f(v.x);
    v.y = v.y > 0.f ? v.y : expm1f(v.y);
    v.z = v.z > 0.f ? v.z : expm1f(v.z);
    v.w = v.w > 0.f ? v.w : expm1f(v.w);
    ((float4*)x)[i] = v;
  }
}

// ---------------- gather layer 2 (bf16 rows) ----------------
__global__ __launch_bounds__(64) void gather2_kernel(const unsigned short* __restrict__ h2,
                                                     const float* __restrict__ as2,
                                                     const float* __restrict__ ad2,
                                                     const int* __restrict__ off,
                                                     const int* __restrict__ elist,
                                                     const float* __restrict__ b2,
                                                     float* __restrict__ out2) {
  int node = blockIdx.x;
  int tid = threadIdx.x;          // 64, 2 channels each
  float ad = ad2[node];
  float as_self = as2[node];
  int s = off[node], e = off[node + 1];
  float m = leaky(as_self + ad);
  for (int i = s; i < e; ++i) m = fmaxf(m, leaky(as2[elist[i]] + ad));
  float a0 = 0.f, a1 = 0.f, z = 0.f;
  {
    float w = __expf(leaky(as_self + ad) - m);
    z += w;
    ushort2 hv = *(const ushort2*)(h2 + (size_t)node * F2 + tid * 2);
    a0 += w * b2f(hv.x); a1 += w * b2f(hv.y);
  }
  for (int i = s; i < e; ++i) {
    int src = elist[i];
    float w = __expf(leaky(as2[src] + ad) - m);
    z += w;
    ushort2 hv = *(const ushort2*)(h2 + (size_t)src * F2 + tid * 2);
    a0 += w * b2f(hv.x); a1 += w * b2f(hv.y);
  }
  float inv = 1.f / z;
  float2 o = make_float2(a0 * inv + b2[tid * 2 + 0], a1 * inv + b2[tid * 2 + 1]);
  *(float2*)(out2 + (size_t)node * F2 + tid * 2) = o;
}

// ---------------- classifier head ----------------
__global__ __launch_bounds__(64) void cls_kernel(const float* __restrict__ h,
                                                 const float* __restrict__ Wc1,
                                                 const float* __restrict__ bc1,
                                                 const float* __restrict__ Wc2,
                                                 const float* __restrict__ bc2,
                                                 float* __restrict__ out) {
  __shared__ float hl[128];
  int node = blockIdx.x;
  int tid = threadIdx.x;          // 64
  hl[tid] = h[(size_t)node * F2 + tid];
  hl[tid + 64] = h[(size_t)node * F2 + 64 + tid];
  __syncthreads();
  float acc = bc1[tid];
#pragma unroll
  for (int k = 0; k < 128; ++k) acc += hl[k] * Wc1[k * 64 + tid];
  acc = fmaxf(acc, 0.f);
  float2 w = *(const float2*)(Wc2 + tid * 2);
  float o0 = acc * w.x, o1 = acc * w.y;
  for (int sh = 32; sh >= 1; sh >>= 1) {
    o0 += __shfl_down(o0, sh, 64);
    o1 += __shfl_down(o1, sh, 64);
  }
  if (tid == 0) {
    out[node * 2 + 0] = o0 + bc2[0];
    out[node * 2 + 1] = o1 + bc2[1];
  }
}

extern "C" void kernel_launch(void* const* d_in, const int* in_sizes, int n_in,
                              void* d_out, int out_size, void* d_ws, size_t ws_size,
                              hipStream_t stream) {
  const float* x        = (const float*)d_in[0];
  const int*   ei_raw   = (const int*)d_in[1];
  const float* W1       = (const float*)d_in[2];
  const float* att_src1 = (const float*)d_in[3];
  const float* att_dst1 = (const float*)d_in[4];
  const float* b1       = (const float*)d_in[5];
  const float* W2       = (const float*)d_in[6];
  const float* att_src2 = (const float*)d_in[7];
  const float* att_dst2 = (const float*)d_in[8];
  const float* b2       = (const float*)d_in[9];
  const float* g1       = (const float*)d_in[10];
  const float* be1      = (const float*)d_in[11];
  const float* g2       = (const float*)d_in[12];
  const float* be2      = (const float*)d_in[13];
  const float* Wc1      = (const float*)d_in[14];
  const float* bc1      = (const float*)d_in[15];
  const float* Wc2      = (const float*)d_in[16];
  const float* bc2      = (const float*)d_in[17];
  float* out = (float*)d_out;

  char* ws = (char*)d_ws;
  size_t o = 0;
  unsigned short* h1b   = (unsigned short*)(ws + o); o += (size_t)N_NODES * F1 * 2;  // 40.96 MB
  unsigned short* out1b = (unsigned short*)(ws + o); o += (size_t)N_NODES * F1 * 2;  // 40.96 MB
  unsigned short* xb    = (unsigned short*)(ws + o); o += (size_t)N_NODES * DIN * 2; // 30.72 MB
  unsigned short* h2b   = (unsigned short*)(ws + o); o += (size_t)N_NODES * F2 * 2;  // 5.12 MB
  float* out2  = (float*)(ws + o); o += (size_t)N_NODES * F2 * 4;                    // 10.24 MB
  float* as1   = (float*)(ws + o); o += (size_t)N_NODES * H1 * 4;
  float* ad1   = (float*)(ws + o); o += (size_t)N_NODES * H1 * 4;
  float* as2   = (float*)(ws + o); o += (size_t)N_NODES * 4;
  float* ad2   = (float*)(ws + o); o += (size_t)N_NODES * 4;
  char*  zbase = ws + o;
  float* bnsum1 = (float*)(ws + o); o += F1 * 2 * 4;
  float* bnsum2 = (float*)(ws + o); o += F2 * 2 * 4;
  int*   deg    = (int*)(ws + o); o += (size_t)N_NODES * 4;
  size_t zbytes = (size_t)((ws + o) - zbase);
  int*   offv   = (int*)(ws + o); o += (size_t)(N_NODES + 4) * 4;
  int*   cursor = (int*)(ws + o); o += (size_t)N_NODES * 4;
  int*   elist  = (int*)(ws + o); o += (size_t)N_EDGES * 4;
  float* ss1    = (float*)(ws + o); o += F1 * 2 * 4;
  float* ss2    = (float*)(ws + o); o += F2 * 2 * 4;
  int*   ei32   = (int*)(ws + o); o += (size_t)2 * N_EDGES * 4;
  unsigned short* W1T = (unsigned short*)(ws + o); o += (size_t)F1 * DIN * 2;
  unsigned short* W2T = (unsigned short*)(ws + o); o += (size_t)F2 * F1 * 2;
  (void)ws_size; (void)in_sizes; (void)n_in; (void)out_size;

  hipMemsetAsync((void*)zbase, 0, zbytes, stream);

  // input conversions
  f2b_kernel<<<2048, 256, 0, stream>>>(x, xb, (size_t)N_NODES * DIN / 4);
  {
    dim3 g1d(F1 / 32, DIN / 32);
    transpose_b_kernel<<<g1d, 256, 0, stream>>>(W1, W1T, DIN, F1);
    dim3 g2d(F2 / 32, F1 / 32);
    transpose_b_kernel<<<g2d, 256, 0, stream>>>(W2, W2T, F1, F2);
  }

  // CSR build
  repack_kernel<<<(2 * N_EDGES + 255) / 256, 256, 0, stream>>>(ei_raw, ei32);
  hist_kernel<<<(N_EDGES + 255) / 256, 256, 0, stream>>>(ei32, deg);
  scan_kernel<<<1, 1024, 0, stream>>>(deg, offv, cursor);
  scatter_kernel<<<(N_EDGES + 255) / 256, 256, 0, stream>>>(ei32, cursor, elist);

  // layer 1: h1 = x @ W1 (bf16 MFMA, fused att logits)
  {
    dim3 grid(F1 / GBN, (N_NODES + GBM - 1) / GBM);
    mfma_gemm_att_kernel<H1><<<grid, 256, 0, stream>>>(
        xb, W1T, h1b, att_src1, att_dst1, as1, ad1, N_NODES, F1, DIN);
  }
  gather1_kernel<<<N_NODES, 256, 0, stream>>>(h1b, as1, ad1, offv, elist, b1, out1b);
  {
    int rows = 79;
    int grid = (N_NODES + rows - 1) / rows;
    bnstats_bf16_kernel<<<grid, 256, 0, stream>>>(out1b, bnsum1, N_NODES, F1, rows);
  }
  bnfinal_kernel<<<(F1 + 255) / 256, 256, 0, stream>>>(bnsum1, g1, be1, ss1, F1);
  bnapply_bf16_kernel<<<2048, 256, 0, stream>>>(out1b, ss1, F1, (size_t)N_NODES * F1 / 4);

  // layer 2: h2 = out1b @ W2 (bf16 MFMA, fused att logits)
  {
    dim3 grid(F2 / GBN, (N_NODES + GBM - 1) / GBM);
    mfma_gemm_att_kernel<1><<<grid, 256, 0, stream>>>(
        out1b, W2T, h2b, att_src2, att_dst2, as2, ad2, N_NODES, F2, F1);
  }
  gather2_kernel<<<N_NODES, 64, 0, stream>>>(h2b, as2, ad2, offv, elist, b2, out2);
  {
    int rows = 79;
    int grid = (N_NODES + rows - 1) / rows;
    bnstats_kernel<1><<<grid, 128, 0, stream>>>(out2, bnsum2, N_NODES, F2, rows);
  }
  bnfinal_kernel<<<1, F2, 0, stream>>>(bnsum2, g2, be2, ss2, F2);
  bnapply_kernel<<<1024, 256, 0, stream>>>(out2, ss2, F2, (size_t)N_NODES * F2 / 4);

  // classifier
  cls_kernel<<<N_NODES, 64, 0, stream>>>(out2, Wc1, bc1, Wc2, bc2, out);
}

// Round 4
// 452.334 us; speedup vs baseline: 2.3271x; 1.0959x over previous
//
#include <hip/hip_runtime.h>
#include <hip/hip_bf16.h>
#include <math.h>

#define N_NODES 20000
#define N_EDGES 320000
#define DIN 768
#define F1 1024   // H1*C1
#define H1 8
#define C1 128
#define F2 128
#define NEG_SLOPE 0.2f
#define BN_EPS 1e-5f
#define RESCALE_THR 8.0f

typedef __attribute__((ext_vector_type(8))) __bf16 bf16x8;
typedef __attribute__((ext_vector_type(4))) float f32x4;

__device__ __forceinline__ float leaky(float x) { return x > 0.f ? x : NEG_SLOPE * x; }

__device__ __forceinline__ unsigned short f2bu(float x) {
  __hip_bfloat16 b = __float2bfloat16(x);
  return *(unsigned short*)&b;
}
__device__ __forceinline__ float b2f(unsigned short u) {
  return __uint_as_float(((unsigned)u) << 16);
}
__device__ __forceinline__ unsigned pack2(float lo, float hi) {
  return (unsigned)f2bu(lo) | ((unsigned)f2bu(hi) << 16);
}

__device__ __forceinline__ void async_copy16(void* lds, const void* g) {
  __builtin_amdgcn_global_load_lds(
      (const __attribute__((address_space(1))) unsigned int*)g,
      (__attribute__((address_space(3))) unsigned int*)lds, 16, 0, 0);
}

// ---------------- edge_index repack (int64 or int32 -> int32) ----------------
__global__ void repack_kernel(const int* raw, int* ei32) {
  int is64 = (raw[1] == 0 && raw[3] == 0 && raw[5] == 0 && raw[7] == 0) ? 1 : 0;
  int e = blockIdx.x * blockDim.x + threadIdx.x;
  if (e < 2 * N_EDGES) {
    ei32[e] = is64 ? raw[2 * e] : raw[e];
  }
}

// ---------------- CSR build ----------------
__global__ void hist_kernel(const int* ei, int* deg) {
  int e = blockIdx.x * blockDim.x + threadIdx.x;
  if (e < N_EDGES) atomicAdd(&deg[ei[N_EDGES + e]], 1);
}

// single-block scan: 1024 threads x 20 nodes each, 2 barriers total
#define NPT 20
__global__ __launch_bounds__(1024) void scan_kernel(const int* __restrict__ deg,
                                                    int* __restrict__ off,
                                                    int* __restrict__ cursor) {
  __shared__ int wsum[16];
  int tid = threadIdx.x;
  int lane = tid & 63, wv = tid >> 6;
  int base = tid * NPT;
  int loc[NPT];
  int run = 0;
#pragma unroll
  for (int k = 0; k < NPT; ++k) {
    int i = base + k;
    int v = (i < N_NODES) ? deg[i] : 0;
    loc[k] = run;
    run += v;
  }
  // wave inclusive scan of per-thread totals
  int incl = run;
  for (int sh = 1; sh < 64; sh <<= 1) {
    int t = __shfl_up(incl, sh, 64);
    if (lane >= sh) incl += t;
  }
  if (lane == 63) wsum[wv] = incl;
  __syncthreads();
  if (wv == 0 && lane < 16) {
    int v = wsum[lane];
    for (int sh = 1; sh < 16; sh <<= 1) {
      int t = __shfl_up(v, sh, 16);
      if (lane >= sh) v += t;
    }
    wsum[lane] = v;  // inclusive wave prefix
  }
  __syncthreads();
  int wbase = (wv > 0) ? wsum[wv - 1] : 0;
  int tbase = wbase + incl - run;  // exclusive prefix for this thread
#pragma unroll
  for (int k = 0; k < NPT; ++k) {
    int i = base + k;
    if (i < N_NODES) {
      int o = tbase + loc[k];
      off[i] = o;
      cursor[i] = o;
    }
  }
  if (tid == 1023) off[N_NODES] = wbase + incl;
}

__global__ void scatter_kernel(const int* ei, int* cursor, int* elist) {
  int e = blockIdx.x * blockDim.x + threadIdx.x;
  if (e < N_EDGES) {
    int dst = ei[N_EDGES + e];
    int p = atomicAdd(&cursor[dst], 1);
    elist[p] = ei[e];
  }
}

// ---------------- fp32 -> bf16 convert ----------------
__global__ void f2b_kernel(const float* __restrict__ in, unsigned short* __restrict__ out,
                           size_t n4) {
  size_t i = (size_t)blockIdx.x * blockDim.x + threadIdx.x;
  size_t stride = (size_t)gridDim.x * blockDim.x;
  for (; i < n4; i += stride) {
    float4 v = ((const float4*)in)[i];
    ushort4 u;
    u.x = f2bu(v.x); u.y = f2bu(v.y); u.z = f2bu(v.z); u.w = f2bu(v.w);
    ((ushort4*)out)[i] = u;
  }
}

// ---------------- transpose + convert: W[K][N] fp32 -> WT[N][K] bf16 ----------------
__global__ void transpose_b_kernel(const float* __restrict__ W, unsigned short* __restrict__ WT,
                                   int K, int N) {
  __shared__ float t[32][33];
  int k0 = blockIdx.y * 32, n0 = blockIdx.x * 32;
  int tx = threadIdx.x & 31, ty = threadIdx.x >> 5;
  for (int i = 0; i < 32; i += 8)
    t[ty + i][tx] = W[(size_t)(k0 + ty + i) * N + n0 + tx];
  __syncthreads();
  for (int i = 0; i < 32; i += 8)
    WT[(size_t)(n0 + ty + i) * K + k0 + tx] = f2bu(t[tx][ty + i]);
}

// ---------------- bf16 MFMA GEMM + fused att-logit epilogue ----------------
#define GBM 128
#define GBN 128
#define GBK 64
template <int H>
__global__ __launch_bounds__(256) void mfma_gemm_att_kernel(
    const unsigned short* __restrict__ A,   // [M][K] bf16
    const unsigned short* __restrict__ BT,  // [N][K] bf16
    unsigned short* __restrict__ C,         // [M][N] bf16
    const float* __restrict__ att_src,      // [N]
    const float* __restrict__ att_dst,      // [N]
    float* __restrict__ as_out,             // [M][H]
    float* __restrict__ ad_out,             // [M][H]
    int M, int N, int K) {
  __shared__ __hip_bfloat16 As[GBM][GBK];
  __shared__ __hip_bfloat16 Bs[GBN][GBK];
  __shared__ float sred[128][2];
  __shared__ float dred[128][2];
  int tid = threadIdx.x;
  int lane = tid & 63, wid = tid >> 6;
  int wr = wid >> 1, wc = wid & 1;                // 2x2 wave grid, 64x64 out each
  int row0 = blockIdx.y * GBM, col0 = blockIdx.x * GBN;
  int head = blockIdx.x;                          // gridDim.x == H
  int l16 = lane & 15, l4 = lane >> 4;
  f32x4 acc[4][4] = {};
  for (int k0 = 0; k0 < K; k0 += GBK) {
#pragma unroll
    for (int j = 0; j < 4; ++j) {
      int c = j * 256 + tid;
      int r = c >> 3, kk = (c & 7) << 3;
      int ga = row0 + r; if (ga >= M) ga = M - 1;
      async_copy16(&As[r][kk], A + (size_t)ga * K + k0 + kk);
      async_copy16(&Bs[r][kk], BT + (size_t)(col0 + r) * K + k0 + kk);
    }
    __syncthreads();
#pragma unroll
    for (int ks = 0; ks < 2; ++ks) {
      bf16x8 af[4], bfr[4];
#pragma unroll
      for (int i = 0; i < 4; ++i)
        af[i] = *(const bf16x8*)&As[wr * 64 + i * 16 + l16][ks * 32 + l4 * 8];
#pragma unroll
      for (int j = 0; j < 4; ++j)
        bfr[j] = *(const bf16x8*)&Bs[wc * 64 + j * 16 + l16][ks * 32 + l4 * 8];
#pragma unroll
      for (int i = 0; i < 4; ++i)
#pragma unroll
        for (int j = 0; j < 4; ++j)
          acc[i][j] = __builtin_amdgcn_mfma_f32_16x16x32_bf16(af[i], bfr[j], acc[i][j], 0, 0, 0);
    }
    __syncthreads();
  }
  // ---- C store (bf16): col=lane&15, row=(lane>>4)*4+r ----
#pragma unroll
  for (int i = 0; i < 4; ++i) {
#pragma unroll
    for (int j = 0; j < 4; ++j) {
#pragma unroll
      for (int r = 0; r < 4; ++r) {
        int row = row0 + wr * 64 + i * 16 + l4 * 4 + r;
        int col = col0 + wc * 64 + j * 16 + l16;
        if (row < M) C[(size_t)row * N + col] = f2bu(acc[i][j][r]);
      }
    }
  }
  // ---- fused attention logits from fp32 accumulators ----
  float avs[4], avd[4];
#pragma unroll
  for (int j = 0; j < 4; ++j) {
    int col = col0 + wc * 64 + j * 16 + l16;
    avs[j] = att_src[col];
    avd[j] = att_dst[col];
  }
#pragma unroll
  for (int i = 0; i < 4; ++i) {
#pragma unroll
    for (int r = 0; r < 4; ++r) {
      float ps = 0.f, pd = 0.f;
#pragma unroll
      for (int j = 0; j < 4; ++j) { ps += acc[i][j][r] * avs[j]; pd += acc[i][j][r] * avd[j]; }
#pragma unroll
      for (int mk = 1; mk < 16; mk <<= 1) {
        ps += __shfl_xor(ps, mk, 64);
        pd += __shfl_xor(pd, mk, 64);
      }
      if (l16 == 0) {
        int lr = wr * 64 + i * 16 + l4 * 4 + r;
        sred[lr][wc] = ps;
        dred[lr][wc] = pd;
      }
    }
  }
  __syncthreads();
  if (tid < 128) {
    int row = row0 + tid;
    if (row < M) {
      as_out[(size_t)row * H + head] = sred[tid][0] + sred[tid][1];
      ad_out[(size_t)row * H + head] = dred[tid][0] + dred[tid][1];
    }
  }
}

// ---------------- gather layer 1: single-pass online softmax, 128 thr/node ----------------
__global__ __launch_bounds__(128) void gather1_kernel(const unsigned short* __restrict__ h1,
                                                      const float* __restrict__ as1,
                                                      const float* __restrict__ ad1,
                                                      const int* __restrict__ off,
                                                      const int* __restrict__ elist,
                                                      const float* __restrict__ b1,
                                                      unsigned short* __restrict__ out1) {
  int node = blockIdx.x;
  int tid = threadIdx.x;           // 128 threads, 8 channels each
  int head = tid >> 4;
  float ad = ad1[node * H1 + head];
  int s = off[node], e = off[node + 1];
  // self-loop initializes the online state
  float m = leaky(as1[node * H1 + head] + ad);
  float z = 1.f;
  float acc[8];
  {
    uint4 u = *(const uint4*)(h1 + (size_t)node * F1 + tid * 8);
    acc[0] = __uint_as_float(u.x << 16); acc[1] = __uint_as_float(u.x & 0xffff0000u);
    acc[2] = __uint_as_float(u.y << 16); acc[3] = __uint_as_float(u.y & 0xffff0000u);
    acc[4] = __uint_as_float(u.z << 16); acc[5] = __uint_as_float(u.z & 0xffff0000u);
    acc[6] = __uint_as_float(u.w << 16); acc[7] = __uint_as_float(u.w & 0xffff0000u);
  }
  // prefetch first edge's src + logit
  int src_n = 0; float e_n = 0.f;
  if (s < e) { src_n = elist[s]; e_n = leaky(as1[src_n * H1 + head] + ad); }
  for (int i = s; i < e; ++i) {
    int src = src_n;
    float el = e_n;
    if (i + 1 < e) { src_n = elist[i + 1]; e_n = leaky(as1[src_n * H1 + head] + ad); }
    float w;
    if (el > m + RESCALE_THR) {
      float r = __expf(m - el);
      z *= r;
#pragma unroll
      for (int k = 0; k < 8; ++k) acc[k] *= r;
      m = el;
      w = 1.f;
    } else {
      w = __expf(el - m);
    }
    z += w;
    uint4 u = *(const uint4*)(h1 + (size_t)src * F1 + tid * 8);
    acc[0] += w * __uint_as_float(u.x << 16); acc[1] += w * __uint_as_float(u.x & 0xffff0000u);
    acc[2] += w * __uint_as_float(u.y << 16); acc[3] += w * __uint_as_float(u.y & 0xffff0000u);
    acc[4] += w * __uint_as_float(u.z << 16); acc[5] += w * __uint_as_float(u.z & 0xffff0000u);
    acc[6] += w * __uint_as_float(u.w << 16); acc[7] += w * __uint_as_float(u.w & 0xffff0000u);
  }
  float inv = 1.f / z;
  const float4 bv0 = *(const float4*)(b1 + tid * 8);
  const float4 bv1 = *(const float4*)(b1 + tid * 8 + 4);
  uint4 o;
  o.x = pack2(acc[0] * inv + bv0.x, acc[1] * inv + bv0.y);
  o.y = pack2(acc[2] * inv + bv0.z, acc[3] * inv + bv0.w);
  o.z = pack2(acc[4] * inv + bv1.x, acc[5] * inv + bv1.y);
  o.w = pack2(acc[6] * inv + bv1.z, acc[7] * inv + bv1.w);
  *(uint4*)(out1 + (size_t)node * F1 + tid * 8) = o;
}

// ---------------- BN statistics, bf16 input ----------------
__global__ void bnstats_bf16_kernel(const unsigned short* __restrict__ x,
                                    float* __restrict__ sums,
                                    int nrows, int F, int rowsPerBlock) {
  int tid = threadIdx.x;
  int c = tid * 4;
  int r0 = blockIdx.x * rowsPerBlock;
  int rend = min(r0 + rowsPerBlock, nrows);
  float s0 = 0.f, s1 = 0.f, s2 = 0.f, s3 = 0.f;
  float q0 = 0.f, q1 = 0.f, q2 = 0.f, q3 = 0.f;
  for (int r = r0; r < rend; ++r) {
    ushort4 u = *(const ushort4*)(x + (size_t)r * F + c);
    float v0 = b2f(u.x), v1 = b2f(u.y), v2 = b2f(u.z), v3 = b2f(u.w);
    s0 += v0; s1 += v1; s2 += v2; s3 += v3;
    q0 += v0 * v0; q1 += v1 * v1; q2 += v2 * v2; q3 += v3 * v3;
  }
  atomicAdd(&sums[c + 0], s0); atomicAdd(&sums[c + 1], s1);
  atomicAdd(&sums[c + 2], s2); atomicAdd(&sums[c + 3], s3);
  atomicAdd(&sums[F + c + 0], q0); atomicAdd(&sums[F + c + 1], q1);
  atomicAdd(&sums[F + c + 2], q2); atomicAdd(&sums[F + c + 3], q3);
}

// fp32-input variant (layer 2, small)
template <int CPT>
__global__ void bnstats_kernel(const float* __restrict__ x, float* __restrict__ sums,
                               int nrows, int F, int rowsPerBlock) {
  int tid = threadIdx.x;
  int r0 = blockIdx.x * rowsPerBlock;
  int rend = min(r0 + rowsPerBlock, nrows);
  float s[CPT], q[CPT];
#pragma unroll
  for (int k = 0; k < CPT; ++k) { s[k] = 0.f; q[k] = 0.f; }
  for (int r = r0; r < rend; ++r) {
    const float* row = x + (size_t)r * F;
#pragma unroll
    for (int k = 0; k < CPT; ++k) {
      float v = row[tid + k * blockDim.x];
      s[k] += v; q[k] += v * v;
    }
  }
#pragma unroll
  for (int k = 0; k < CPT; ++k) {
    atomicAdd(&sums[tid + k * blockDim.x], s[k]);
    atomicAdd(&sums[F + tid + k * blockDim.x], q[k]);
  }
}

__global__ void bnfinal_kernel(const float* __restrict__ sums, const float* __restrict__ g,
                               const float* __restrict__ be, float* __restrict__ ss, int F) {
  int c = blockIdx.x * blockDim.x + threadIdx.x;
  if (c < F) {
    float mu = sums[c] * (1.f / N_NODES);
    float var = sums[F + c] * (1.f / N_NODES) - mu * mu;
    float sc = g[c] * rsqrtf(var + BN_EPS);
    ss[c] = sc;
    ss[F + c] = be[c] - mu * sc;
  }
}

// BN apply + ELU, bf16 in-place (layer 1, feeds GEMM2)
__global__ void bnapply_bf16_kernel(unsigned short* __restrict__ x, const float* __restrict__ ss,
                                    int F, size_t total4) {
  size_t i = (size_t)blockIdx.x * blockDim.x + threadIdx.x;
  size_t stride = (size_t)gridDim.x * blockDim.x;
  for (; i < total4; i += stride) {
    int c = (int)((i * 4) & (size_t)(F - 1));
    ushort4 u = ((ushort4*)x)[i];
    float v0 = b2f(u.x) * ss[c + 0] + ss[F + c + 0];
    float v1 = b2f(u.y) * ss[c + 1] + ss[F + c + 1];
    float v2 = b2f(u.z) * ss[c + 2] + ss[F + c + 2];
    float v3 = b2f(u.w) * ss[c + 3] + ss[F + c + 3];
    v0 = v0 > 0.f ? v0 : expm1f(v0);
    v1 = v1 > 0.f ? v1 : expm1f(v1);
    v2 = v2 > 0.f ? v2 : expm1f(v2);
    v3 = v3 > 0.f ? v3 : expm1f(v3);
    u.x = f2bu(v0); u.y = f2bu(v1); u.z = f2bu(v2); u.w = f2bu(v3);
    ((ushort4*)x)[i] = u;
  }
}

// BN apply + ELU, fp32 in-place (layer 2)
__global__ void bnapply_kernel(float* __restrict__ x, const float* __restrict__ ss,
                               int F, size_t total4) {
  size_t i = (size_t)blockIdx.x * blockDim.x + threadIdx.x;
  size_t stride = (size_t)gridDim.x * blockDim.x;
  for (; i < total4; i += stride) {
    int c = (int)((i * 4) & (size_t)(F - 1));
    float4 v = ((float4*)x)[i];
    v.x = v.x * ss[c + 0] + ss[F + c + 0];
    v.y = v.y * ss[c + 1] + ss[F + c + 1];
    v.z = v.z * ss[c + 2] + ss[F + c + 2];
    v.w = v.w * ss[c + 3] + ss[F + c + 3];
    v.x = v.x > 0.f ? v.x : expm1f(v.x);
    v.y = v.y > 0.f ? v.y : expm1f(v.y);
    v.z = v.z > 0.f ? v.z : expm1f(v.z);
    v.w = v.w > 0.f ? v.w : expm1f(v.w);
    ((float4*)x)[i] = v;
  }
}

// ---------------- gather layer 2: single-pass online softmax ----------------
__global__ __launch_bounds__(64) void gather2_kernel(const unsigned short* __restrict__ h2,
                                                     const float* __restrict__ as2,
                                                     const float* __restrict__ ad2,
                                                     const int* __restrict__ off,
                                                     const int* __restrict__ elist,
                                                     const float* __restrict__ b2,
                                                     float* __restrict__ out2) {
  int node = blockIdx.x;
  int tid = threadIdx.x;          // 64, 2 channels each
  float ad = ad2[node];
  int s = off[node], e = off[node + 1];
  float m = leaky(as2[node] + ad);
  float z = 1.f;
  float a0, a1;
  {
    unsigned u = *(const unsigned*)(h2 + (size_t)node * F2 + tid * 2);
    a0 = __uint_as_float(u << 16); a1 = __uint_as_float(u & 0xffff0000u);
  }
  int src_n = 0; float e_n = 0.f;
  if (s < e) { src_n = elist[s]; e_n = leaky(as2[src_n] + ad); }
  for (int i = s; i < e; ++i) {
    int src = src_n;
    float el = e_n;
    if (i + 1 < e) { src_n = elist[i + 1]; e_n = leaky(as2[src_n] + ad); }
    float w;
    if (el > m + RESCALE_THR) {
      float r = __expf(m - el);
      z *= r; a0 *= r; a1 *= r;
      m = el; w = 1.f;
    } else {
      w = __expf(el - m);
    }
    z += w;
    unsigned u = *(const unsigned*)(h2 + (size_t)src * F2 + tid * 2);
    a0 += w * __uint_as_float(u << 16);
    a1 += w * __uint_as_float(u & 0xffff0000u);
  }
  float inv = 1.f / z;
  float2 o = make_float2(a0 * inv + b2[tid * 2 + 0], a1 * inv + b2[tid * 2 + 1]);
  *(float2*)(out2 + (size_t)node * F2 + tid * 2) = o;
}

// ---------------- classifier head ----------------
__global__ __launch_bounds__(64) void cls_kernel(const float* __restrict__ h,
                                                 const float* __restrict__ Wc1,
                                                 const float* __restrict__ bc1,
                                                 const float* __restrict__ Wc2,
                                                 const float* __restrict__ bc2,
                                                 float* __restrict__ out) {
  __shared__ float hl[128];
  int node = blockIdx.x;
  int tid = threadIdx.x;          // 64
  hl[tid] = h[(size_t)node * F2 + tid];
  hl[tid + 64] = h[(size_t)node * F2 + 64 + tid];
  __syncthreads();
  float acc = bc1[tid];
#pragma unroll
  for (int k = 0; k < 128; ++k) acc += hl[k] * Wc1[k * 64 + tid];
  acc = fmaxf(acc, 0.f);
  float2 w = *(const float2*)(Wc2 + tid * 2);
  float o0 = acc * w.x, o1 = acc * w.y;
  for (int sh = 32; sh >= 1; sh >>= 1) {
    o0 += __shfl_down(o0, sh, 64);
    o1 += __shfl_down(o1, sh, 64);
  }
  if (tid == 0) {
    out[node * 2 + 0] = o0 + bc2[0];
    out[node * 2 + 1] = o1 + bc2[1];
  }
}

extern "C" void kernel_launch(void* const* d_in, const int* in_sizes, int n_in,
                              void* d_out, int out_size, void* d_ws, size_t ws_size,
                              hipStream_t stream) {
  const float* x        = (const float*)d_in[0];
  const int*   ei_raw   = (const int*)d_in[1];
  const float* W1       = (const float*)d_in[2];
  const float* att_src1 = (const float*)d_in[3];
  const float* att_dst1 = (const float*)d_in[4];
  const float* b1       = (const float*)d_in[5];
  const float* W2       = (const float*)d_in[6];
  const float* att_src2 = (const float*)d_in[7];
  const float* att_dst2 = (const float*)d_in[8];
  const float* b2       = (const float*)d_in[9];
  const float* g1       = (const float*)d_in[10];
  const float* be1      = (const float*)d_in[11];
  const float* g2       = (const float*)d_in[12];
  const float* be2      = (const float*)d_in[13];
  const float* Wc1      = (const float*)d_in[14];
  const float* bc1      = (const float*)d_in[15];
  const float* Wc2      = (const float*)d_in[16];
  const float* bc2      = (const float*)d_in[17];
  float* out = (float*)d_out;

  char* ws = (char*)d_ws;
  size_t o = 0;
  unsigned short* h1b   = (unsigned short*)(ws + o); o += (size_t)N_NODES * F1 * 2;  // 40.96 MB
  unsigned short* out1b = (unsigned short*)(ws + o); o += (size_t)N_NODES * F1 * 2;  // 40.96 MB
  unsigned short* xb    = (unsigned short*)(ws + o); o += (size_t)N_NODES * DIN * 2; // 30.72 MB
  unsigned short* h2b   = (unsigned short*)(ws + o); o += (size_t)N_NODES * F2 * 2;  // 5.12 MB
  float* out2  = (float*)(ws + o); o += (size_t)N_NODES * F2 * 4;                    // 10.24 MB
  float* as1   = (float*)(ws + o); o += (size_t)N_NODES * H1 * 4;
  float* ad1   = (float*)(ws + o); o += (size_t)N_NODES * H1 * 4;
  float* as2   = (float*)(ws + o); o += (size_t)N_NODES * 4;
  float* ad2   = (float*)(ws + o); o += (size_t)N_NODES * 4;
  char*  zbase = ws + o;
  float* bnsum1 = (float*)(ws + o); o += F1 * 2 * 4;
  float* bnsum2 = (float*)(ws + o); o += F2 * 2 * 4;
  int*   deg    = (int*)(ws + o); o += (size_t)N_NODES * 4;
  size_t zbytes = (size_t)((ws + o) - zbase);
  int*   offv   = (int*)(ws + o); o += (size_t)(N_NODES + 4) * 4;
  int*   cursor = (int*)(ws + o); o += (size_t)N_NODES * 4;
  int*   elist  = (int*)(ws + o); o += (size_t)N_EDGES * 4;
  float* ss1    = (float*)(ws + o); o += F1 * 2 * 4;
  float* ss2    = (float*)(ws + o); o += F2 * 2 * 4;
  int*   ei32   = (int*)(ws + o); o += (size_t)2 * N_EDGES * 4;
  unsigned short* W1T = (unsigned short*)(ws + o); o += (size_t)F1 * DIN * 2;
  unsigned short* W2T = (unsigned short*)(ws + o); o += (size_t)F2 * F1 * 2;
  (void)ws_size; (void)in_sizes; (void)n_in; (void)out_size;

  hipMemsetAsync((void*)zbase, 0, zbytes, stream);

  // input conversions
  f2b_kernel<<<2048, 256, 0, stream>>>(x, xb, (size_t)N_NODES * DIN / 4);
  {
    dim3 g1d(F1 / 32, DIN / 32);
    transpose_b_kernel<<<g1d, 256, 0, stream>>>(W1, W1T, DIN, F1);
    dim3 g2d(F2 / 32, F1 / 32);
    transpose_b_kernel<<<g2d, 256, 0, stream>>>(W2, W2T, F1, F2);
  }

  // CSR build
  repack_kernel<<<(2 * N_EDGES + 255) / 256, 256, 0, stream>>>(ei_raw, ei32);
  hist_kernel<<<(N_EDGES + 255) / 256, 256, 0, stream>>>(ei32, deg);
  scan_kernel<<<1, 1024, 0, stream>>>(deg, offv, cursor);
  scatter_kernel<<<(N_EDGES + 255) / 256, 256, 0, stream>>>(ei32, cursor, elist);

  // layer 1: h1 = x @ W1 (bf16 MFMA, fused att logits)
  {
    dim3 grid(F1 / GBN, (N_NODES + GBM - 1) / GBM);
    mfma_gemm_att_kernel<H1><<<grid, 256, 0, stream>>>(
        xb, W1T, h1b, att_src1, att_dst1, as1, ad1, N_NODES, F1, DIN);
  }
  gather1_kernel<<<N_NODES, 128, 0, stream>>>(h1b, as1, ad1, offv, elist, b1, out1b);
  {
    int rows = 79;
    int grid = (N_NODES + rows - 1) / rows;
    bnstats_bf16_kernel<<<grid, 256, 0, stream>>>(out1b, bnsum1, N_NODES, F1, rows);
  }
  bnfinal_kernel<<<(F1 + 255) / 256, 256, 0, stream>>>(bnsum1, g1, be1, ss1, F1);
  bnapply_bf16_kernel<<<2048, 256, 0, stream>>>(out1b, ss1, F1, (size_t)N_NODES * F1 / 4);

  // layer 2: h2 = out1b @ W2 (bf16 MFMA, fused att logits)
  {
    dim3 grid(F2 / GBN, (N_NODES + GBM - 1) / GBM);
    mfma_gemm_att_kernel<1><<<grid, 256, 0, stream>>>(
        out1b, W2T, h2b, att_src2, att_dst2, as2, ad2, N_NODES, F2, F1);
  }
  gather2_kernel<<<N_NODES, 64, 0, stream>>>(h2b, as2, ad2, offv, elist, b2, out2);
  {
    int rows = 79;
    int grid = (N_NODES + rows - 1) / rows;
    bnstats_kernel<1><<<grid, 128, 0, stream>>>(out2, bnsum2, N_NODES, F2, rows);
  }
  bnfinal_kernel<<<1, F2, 0, stream>>>(bnsum2, g2, be2, ss2, F2);
  bnapply_kernel<<<1024, 256, 0, stream>>>(out2, ss2, F2, (size_t)N_NODES * F2 / 4);

  // classifier
  cls_kernel<<<N_NODES, 64, 0, stream>>>(out2, Wc1, bc1, Wc2, bc2, out);
}

// Round 5
// 429.579 us; speedup vs baseline: 2.4504x; 1.0530x over previous
//
#include <hip/hip_runtime.h>
#include <hip/hip_bf16.h>
#include <math.h>

#define N_NODES 20000
#define N_EDGES 320000
#define DIN 768
#define F1 1024   // H1*C1
#define H1 8
#define C1 128
#define F2 128
#define NEG_SLOPE 0.2f
#define BN_EPS 1e-5f
#define RESCALE_THR 8.0f

typedef __attribute__((ext_vector_type(8))) __bf16 bf16x8;
typedef __attribute__((ext_vector_type(4))) float f32x4;

__device__ __forceinline__ float leaky(float x) { return x > 0.f ? x : NEG_SLOPE * x; }

__device__ __forceinline__ unsigned short f2bu(float x) {
  __hip_bfloat16 b = __float2bfloat16(x);
  return *(unsigned short*)&b;
}
__device__ __forceinline__ float b2f(unsigned short u) {
  return __uint_as_float(((unsigned)u) << 16);
}
__device__ __forceinline__ unsigned pack2(float lo, float hi) {
  return (unsigned)f2bu(lo) | ((unsigned)f2bu(hi) << 16);
}

__device__ __forceinline__ void async_copy16(void* lds, const void* g) {
  __builtin_amdgcn_global_load_lds(
      (const __attribute__((address_space(1))) unsigned int*)g,
      (__attribute__((address_space(3))) unsigned int*)lds, 16, 0, 0);
}

// ---------------- edge_index repack + dst histogram (fused) ----------------
__global__ void repack_hist_kernel(const int* raw, int* ei32, int* deg) {
  int is64 = (raw[1] == 0 && raw[3] == 0 && raw[5] == 0 && raw[7] == 0) ? 1 : 0;
  int e = blockIdx.x * blockDim.x + threadIdx.x;
  if (e < 2 * N_EDGES) {
    int v = is64 ? raw[2 * e] : raw[e];
    ei32[e] = v;
    if (e >= N_EDGES) atomicAdd(&deg[v], 1);   // dst half
  }
}

// single-block scan: 1024 threads x 20 nodes each, 2 barriers total
#define NPT 20
__global__ __launch_bounds__(1024) void scan_kernel(const int* __restrict__ deg,
                                                    int* __restrict__ off,
                                                    int* __restrict__ cursor) {
  __shared__ int wsum[16];
  int tid = threadIdx.x;
  int lane = tid & 63, wv = tid >> 6;
  int base = tid * NPT;
  int loc[NPT];
  int run = 0;
#pragma unroll
  for (int k = 0; k < NPT; ++k) {
    int i = base + k;
    int v = (i < N_NODES) ? deg[i] : 0;
    loc[k] = run;
    run += v;
  }
  int incl = run;
  for (int sh = 1; sh < 64; sh <<= 1) {
    int t = __shfl_up(incl, sh, 64);
    if (lane >= sh) incl += t;
  }
  if (lane == 63) wsum[wv] = incl;
  __syncthreads();
  if (wv == 0 && lane < 16) {
    int v = wsum[lane];
    for (int sh = 1; sh < 16; sh <<= 1) {
      int t = __shfl_up(v, sh, 16);
      if (lane >= sh) v += t;
    }
    wsum[lane] = v;
  }
  __syncthreads();
  int wbase = (wv > 0) ? wsum[wv - 1] : 0;
  int tbase = wbase + incl - run;
#pragma unroll
  for (int k = 0; k < NPT; ++k) {
    int i = base + k;
    if (i < N_NODES) {
      int o = tbase + loc[k];
      off[i] = o;
      cursor[i] = o;
    }
  }
  if (tid == 1023) off[N_NODES] = wbase + incl;
}

__global__ void scatter_kernel(const int* ei, int* cursor, int* elist) {
  int e = blockIdx.x * blockDim.x + threadIdx.x;
  if (e < N_EDGES) {
    int dst = ei[N_EDGES + e];
    int p = atomicAdd(&cursor[dst], 1);
    elist[p] = ei[e];
  }
}

// ---------------- fp32 -> bf16 convert ----------------
__global__ void f2b_kernel(const float* __restrict__ in, unsigned short* __restrict__ out,
                           size_t n4) {
  size_t i = (size_t)blockIdx.x * blockDim.x + threadIdx.x;
  size_t stride = (size_t)gridDim.x * blockDim.x;
  for (; i < n4; i += stride) {
    float4 v = ((const float4*)in)[i];
    ushort4 u;
    u.x = f2bu(v.x); u.y = f2bu(v.y); u.z = f2bu(v.z); u.w = f2bu(v.w);
    ((ushort4*)out)[i] = u;
  }
}

// ---------------- transpose + convert: W[K][N] fp32 -> WT[N][K] bf16 ----------------
__global__ void transpose_b_kernel(const float* __restrict__ W, unsigned short* __restrict__ WT,
                                   int K, int N) {
  __shared__ float t[32][33];
  int k0 = blockIdx.y * 32, n0 = blockIdx.x * 32;
  int tx = threadIdx.x & 31, ty = threadIdx.x >> 5;
  for (int i = 0; i < 32; i += 8)
    t[ty + i][tx] = W[(size_t)(k0 + ty + i) * N + n0 + tx];
  __syncthreads();
  for (int i = 0; i < 32; i += 8)
    WT[(size_t)(n0 + ty + i) * K + k0 + tx] = f2bu(t[tx][ty + i]);
}

// ---------------- bf16 MFMA GEMM + fused att-logit epilogue ----------------
#define GBM 128
#define GBN 128
#define GBK 64
template <int H>
__global__ __launch_bounds__(256) void mfma_gemm_att_kernel(
    const unsigned short* __restrict__ A,   // [M][K] bf16
    const unsigned short* __restrict__ BT,  // [N][K] bf16
    unsigned short* __restrict__ C,         // [M][N] bf16
    const float* __restrict__ att_src,      // [N]
    const float* __restrict__ att_dst,      // [N]
    float* __restrict__ as_out,             // [M][H]
    float* __restrict__ ad_out,             // [M][H]
    int M, int N, int K) {
  __shared__ __hip_bfloat16 As[GBM][GBK];
  __shared__ __hip_bfloat16 Bs[GBN][GBK];
  __shared__ float sred[128][2];
  __shared__ float dred[128][2];
  int tid = threadIdx.x;
  int lane = tid & 63, wid = tid >> 6;
  int wr = wid >> 1, wc = wid & 1;                // 2x2 wave grid, 64x64 out each
  int row0 = blockIdx.y * GBM, col0 = blockIdx.x * GBN;
  int head = blockIdx.x;                          // gridDim.x == H
  int l16 = lane & 15, l4 = lane >> 4;
  f32x4 acc[4][4] = {};
  for (int k0 = 0; k0 < K; k0 += GBK) {
#pragma unroll
    for (int j = 0; j < 4; ++j) {
      int c = j * 256 + tid;
      int r = c >> 3, kk = (c & 7) << 3;
      int ga = row0 + r; if (ga >= M) ga = M - 1;
      async_copy16(&As[r][kk], A + (size_t)ga * K + k0 + kk);
      async_copy16(&Bs[r][kk], BT + (size_t)(col0 + r) * K + k0 + kk);
    }
    __syncthreads();
#pragma unroll
    for (int ks = 0; ks < 2; ++ks) {
      bf16x8 af[4], bfr[4];
#pragma unroll
      for (int i = 0; i < 4; ++i)
        af[i] = *(const bf16x8*)&As[wr * 64 + i * 16 + l16][ks * 32 + l4 * 8];
#pragma unroll
      for (int j = 0; j < 4; ++j)
        bfr[j] = *(const bf16x8*)&Bs[wc * 64 + j * 16 + l16][ks * 32 + l4 * 8];
#pragma unroll
      for (int i = 0; i < 4; ++i)
#pragma unroll
        for (int j = 0; j < 4; ++j)
          acc[i][j] = __builtin_amdgcn_mfma_f32_16x16x32_bf16(af[i], bfr[j], acc[i][j], 0, 0, 0);
    }
    __syncthreads();
  }
  // ---- C store (bf16): col=lane&15, row=(lane>>4)*4+r ----
#pragma unroll
  for (int i = 0; i < 4; ++i) {
#pragma unroll
    for (int j = 0; j < 4; ++j) {
#pragma unroll
      for (int r = 0; r < 4; ++r) {
        int row = row0 + wr * 64 + i * 16 + l4 * 4 + r;
        int col = col0 + wc * 64 + j * 16 + l16;
        if (row < M) C[(size_t)row * N + col] = f2bu(acc[i][j][r]);
      }
    }
  }
  // ---- fused attention logits from fp32 accumulators ----
  float avs[4], avd[4];
#pragma unroll
  for (int j = 0; j < 4; ++j) {
    int col = col0 + wc * 64 + j * 16 + l16;
    avs[j] = att_src[col];
    avd[j] = att_dst[col];
  }
#pragma unroll
  for (int i = 0; i < 4; ++i) {
#pragma unroll
    for (int r = 0; r < 4; ++r) {
      float ps = 0.f, pd = 0.f;
#pragma unroll
      for (int j = 0; j < 4; ++j) { ps += acc[i][j][r] * avs[j]; pd += acc[i][j][r] * avd[j]; }
#pragma unroll
      for (int mk = 1; mk < 16; mk <<= 1) {
        ps += __shfl_xor(ps, mk, 64);
        pd += __shfl_xor(pd, mk, 64);
      }
      if (l16 == 0) {
        int lr = wr * 64 + i * 16 + l4 * 4 + r;
        sred[lr][wc] = ps;
        dred[lr][wc] = pd;
      }
    }
  }
  __syncthreads();
  if (tid < 128) {
    int row = row0 + tid;
    if (row < M) {
      as_out[(size_t)row * H + head] = sred[tid][0] + sred[tid][1];
      ad_out[(size_t)row * H + head] = dred[tid][0] + dred[tid][1];
    }
  }
}

// ---------------- gather layer 1: online softmax, 3-stage pipeline ----------------
// stage layout per iteration i: consume row/logit for edge i (regs rA,eA);
// row for edge i+1 in flight; row for edge i+2 issued this iteration;
// elist+logit chain for edge i+3 issued this iteration.
__global__ __launch_bounds__(128) void gather1_kernel(const unsigned short* __restrict__ h1,
                                                      const float* __restrict__ as1,
                                                      const float* __restrict__ ad1,
                                                      const int* __restrict__ off,
                                                      const int* __restrict__ elist,
                                                      const float* __restrict__ b1,
                                                      unsigned short* __restrict__ out1) {
  int node = blockIdx.x;
  int tid = threadIdx.x;           // 128 threads, 8 channels each
  int head = tid >> 4;
  const float ad = ad1[node * H1 + head];
  int s = off[node], e = off[node + 1];
  float m = leaky(as1[node * H1 + head] + ad);
  float z = 1.f;
  float acc[8];
  {
    uint4 u = *(const uint4*)(h1 + (size_t)node * F1 + tid * 8);
    acc[0] = __uint_as_float(u.x << 16); acc[1] = __uint_as_float(u.x & 0xffff0000u);
    acc[2] = __uint_as_float(u.y << 16); acc[3] = __uint_as_float(u.y & 0xffff0000u);
    acc[4] = __uint_as_float(u.z << 16); acc[5] = __uint_as_float(u.z & 0xffff0000u);
    acc[6] = __uint_as_float(u.w << 16); acc[7] = __uint_as_float(u.w & 0xffff0000u);
  }
  int sB = 0, sC = 0;
  float eA = 0.f, eB = 0.f, eC = 0.f;
  uint4 rA = {}, rB = {};
  if (s < e) {
    int sA = elist[s];
    eA = leaky(as1[sA * H1 + head] + ad);
    rA = *(const uint4*)(h1 + (size_t)sA * F1 + tid * 8);
  }
  if (s + 1 < e) {
    sB = elist[s + 1];
    eB = leaky(as1[sB * H1 + head] + ad);
    rB = *(const uint4*)(h1 + (size_t)sB * F1 + tid * 8);
  }
  if (s + 2 < e) {
    sC = elist[s + 2];
    eC = leaky(as1[sC * H1 + head] + ad);
  }
  for (int i = s; i < e; ++i) {
    uint4 u = rA; float el = eA;
    // advance pipeline
    rA = rB; eA = eB;
    sB = sC; eB = eC;
    if (i + 2 < e) rB = *(const uint4*)(h1 + (size_t)sB * F1 + tid * 8);
    if (i + 3 < e) { sC = elist[i + 3]; eC = leaky(as1[sC * H1 + head] + ad); }
    float w;
    if (el > m + RESCALE_THR) {
      float r = __expf(m - el);
      z *= r;
#pragma unroll
      for (int k = 0; k < 8; ++k) acc[k] *= r;
      m = el;
      w = 1.f;
    } else {
      w = __expf(el - m);
    }
    z += w;
    acc[0] += w * __uint_as_float(u.x << 16); acc[1] += w * __uint_as_float(u.x & 0xffff0000u);
    acc[2] += w * __uint_as_float(u.y << 16); acc[3] += w * __uint_as_float(u.y & 0xffff0000u);
    acc[4] += w * __uint_as_float(u.z << 16); acc[5] += w * __uint_as_float(u.z & 0xffff0000u);
    acc[6] += w * __uint_as_float(u.w << 16); acc[7] += w * __uint_as_float(u.w & 0xffff0000u);
  }
  float inv = 1.f / z;
  const float4 bv0 = *(const float4*)(b1 + tid * 8);
  const float4 bv1 = *(const float4*)(b1 + tid * 8 + 4);
  uint4 o;
  o.x = pack2(acc[0] * inv + bv0.x, acc[1] * inv + bv0.y);
  o.y = pack2(acc[2] * inv + bv0.z, acc[3] * inv + bv0.w);
  o.z = pack2(acc[4] * inv + bv1.x, acc[5] * inv + bv1.y);
  o.w = pack2(acc[6] * inv + bv1.z, acc[7] * inv + bv1.w);
  *(uint4*)(out1 + (size_t)node * F1 + tid * 8) = o;
}

// ---------------- BN statistics, bf16 input ----------------
__global__ void bnstats_bf16_kernel(const unsigned short* __restrict__ x,
                                    float* __restrict__ sums,
                                    int nrows, int F, int rowsPerBlock) {
  int tid = threadIdx.x;
  int c = tid * 4;
  int r0 = blockIdx.x * rowsPerBlock;
  int rend = min(r0 + rowsPerBlock, nrows);
  float s0 = 0.f, s1 = 0.f, s2 = 0.f, s3 = 0.f;
  float q0 = 0.f, q1 = 0.f, q2 = 0.f, q3 = 0.f;
  for (int r = r0; r < rend; ++r) {
    ushort4 u = *(const ushort4*)(x + (size_t)r * F + c);
    float v0 = b2f(u.x), v1 = b2f(u.y), v2 = b2f(u.z), v3 = b2f(u.w);
    s0 += v0; s1 += v1; s2 += v2; s3 += v3;
    q0 += v0 * v0; q1 += v1 * v1; q2 += v2 * v2; q3 += v3 * v3;
  }
  atomicAdd(&sums[c + 0], s0); atomicAdd(&sums[c + 1], s1);
  atomicAdd(&sums[c + 2], s2); atomicAdd(&sums[c + 3], s3);
  atomicAdd(&sums[F + c + 0], q0); atomicAdd(&sums[F + c + 1], q1);
  atomicAdd(&sums[F + c + 2], q2); atomicAdd(&sums[F + c + 3], q3);
}

// fp32-input variant (layer 2, small)
template <int CPT>
__global__ void bnstats_kernel(const float* __restrict__ x, float* __restrict__ sums,
                               int nrows, int F, int rowsPerBlock) {
  int tid = threadIdx.x;
  int r0 = blockIdx.x * rowsPerBlock;
  int rend = min(r0 + rowsPerBlock, nrows);
  float s[CPT], q[CPT];
#pragma unroll
  for (int k = 0; k < CPT; ++k) { s[k] = 0.f; q[k] = 0.f; }
  for (int r = r0; r < rend; ++r) {
    const float* row = x + (size_t)r * F;
#pragma unroll
    for (int k = 0; k < CPT; ++k) {
      float v = row[tid + k * blockDim.x];
      s[k] += v; q[k] += v * v;
    }
  }
#pragma unroll
  for (int k = 0; k < CPT; ++k) {
    atomicAdd(&sums[tid + k * blockDim.x], s[k]);
    atomicAdd(&sums[F + tid + k * blockDim.x], q[k]);
  }
}

__global__ void bnfinal_kernel(const float* __restrict__ sums, const float* __restrict__ g,
                               const float* __restrict__ be, float* __restrict__ ss, int F) {
  int c = blockIdx.x * blockDim.x + threadIdx.x;
  if (c < F) {
    float mu = sums[c] * (1.f / N_NODES);
    float var = sums[F + c] * (1.f / N_NODES) - mu * mu;
    float sc = g[c] * rsqrtf(var + BN_EPS);
    ss[c] = sc;
    ss[F + c] = be[c] - mu * sc;
  }
}

// BN apply + ELU, bf16 in-place (layer 1, feeds GEMM2)
__global__ void bnapply_bf16_kernel(unsigned short* __restrict__ x, const float* __restrict__ ss,
                                    int F, size_t total4) {
  size_t i = (size_t)blockIdx.x * blockDim.x + threadIdx.x;
  size_t stride = (size_t)gridDim.x * blockDim.x;
  for (; i < total4; i += stride) {
    int c = (int)((i * 4) & (size_t)(F - 1));
    ushort4 u = ((ushort4*)x)[i];
    float v0 = b2f(u.x) * ss[c + 0] + ss[F + c + 0];
    float v1 = b2f(u.y) * ss[c + 1] + ss[F + c + 1];
    float v2 = b2f(u.z) * ss[c + 2] + ss[F + c + 2];
    float v3 = b2f(u.w) * ss[c + 3] + ss[F + c + 3];
    v0 = v0 > 0.f ? v0 : expm1f(v0);
    v1 = v1 > 0.f ? v1 : expm1f(v1);
    v2 = v2 > 0.f ? v2 : expm1f(v2);
    v3 = v3 > 0.f ? v3 : expm1f(v3);
    u.x = f2bu(v0); u.y = f2bu(v1); u.z = f2bu(v2); u.w = f2bu(v3);
    ((ushort4*)x)[i] = u;
  }
}

// ---------------- gather layer 2: online softmax, 3-stage pipeline ----------------
__global__ __launch_bounds__(64) void gather2_kernel(const unsigned short* __restrict__ h2,
                                                     const float* __restrict__ as2,
                                                     const float* __restrict__ ad2,
                                                     const int* __restrict__ off,
                                                     const int* __restrict__ elist,
                                                     const float* __restrict__ b2,
                                                     float* __restrict__ out2) {
  int node = blockIdx.x;
  int tid = threadIdx.x;          // 64, 2 channels each
  const float ad = ad2[node];
  int s = off[node], e = off[node + 1];
  float m = leaky(as2[node] + ad);
  float z = 1.f;
  float a0, a1;
  {
    unsigned u = *(const unsigned*)(h2 + (size_t)node * F2 + tid * 2);
    a0 = __uint_as_float(u << 16); a1 = __uint_as_float(u & 0xffff0000u);
  }
  int sB = 0, sC = 0;
  float eA = 0.f, eB = 0.f, eC = 0.f;
  unsigned rA = 0, rB = 0;
  if (s < e) {
    int sA = elist[s];
    eA = leaky(as2[sA] + ad);
    rA = *(const unsigned*)(h2 + (size_t)sA * F2 + tid * 2);
  }
  if (s + 1 < e) {
    sB = elist[s + 1];
    eB = leaky(as2[sB] + ad);
    rB = *(const unsigned*)(h2 + (size_t)sB * F2 + tid * 2);
  }
  if (s + 2 < e) {
    sC = elist[s + 2];
    eC = leaky(as2[sC] + ad);
  }
  for (int i = s; i < e; ++i) {
    unsigned u = rA; float el = eA;
    rA = rB; eA = eB;
    sB = sC; eB = eC;
    if (i + 2 < e) rB = *(const unsigned*)(h2 + (size_t)sB * F2 + tid * 2);
    if (i + 3 < e) { sC = elist[i + 3]; eC = leaky(as2[sC] + ad); }
    float w;
    if (el > m + RESCALE_THR) {
      float r = __expf(m - el);
      z *= r; a0 *= r; a1 *= r;
      m = el; w = 1.f;
    } else {
      w = __expf(el - m);
    }
    z += w;
    a0 += w * __uint_as_float(u << 16);
    a1 += w * __uint_as_float(u & 0xffff0000u);
  }
  float inv = 1.f / z;
  float2 o = make_float2(a0 * inv + b2[tid * 2 + 0], a1 * inv + b2[tid * 2 + 1]);
  *(float2*)(out2 + (size_t)node * F2 + tid * 2) = o;
}

// ---------------- classifier head (fused BN2 apply + ELU) ----------------
__global__ __launch_bounds__(64) void cls_kernel(const float* __restrict__ h,
                                                 const float* __restrict__ ss2,
                                                 const float* __restrict__ Wc1,
                                                 const float* __restrict__ bc1,
                                                 const float* __restrict__ Wc2,
                                                 const float* __restrict__ bc2,
                                                 float* __restrict__ out) {
  __shared__ float hl[128];
  int node = blockIdx.x;
  int tid = threadIdx.x;          // 64
  {
    float v = h[(size_t)node * F2 + tid] * ss2[tid] + ss2[F2 + tid];
    v = v > 0.f ? v : expm1f(v);
    hl[tid] = v;
    float v2 = h[(size_t)node * F2 + 64 + tid] * ss2[64 + tid] + ss2[F2 + 64 + tid];
    v2 = v2 > 0.f ? v2 : expm1f(v2);
    hl[tid + 64] = v2;
  }
  __syncthreads();
  float acc = bc1[tid];
#pragma unroll
  for (int k = 0; k < 128; ++k) acc += hl[k] * Wc1[k * 64 + tid];
  acc = fmaxf(acc, 0.f);
  float2 w = *(const float2*)(Wc2 + tid * 2);
  float o0 = acc * w.x, o1 = acc * w.y;
  for (int sh = 32; sh >= 1; sh >>= 1) {
    o0 += __shfl_down(o0, sh, 64);
    o1 += __shfl_down(o1, sh, 64);
  }
  if (tid == 0) {
    out[node * 2 + 0] = o0 + bc2[0];
    out[node * 2 + 1] = o1 + bc2[1];
  }
}

extern "C" void kernel_launch(void* const* d_in, const int* in_sizes, int n_in,
                              void* d_out, int out_size, void* d_ws, size_t ws_size,
                              hipStream_t stream) {
  const float* x        = (const float*)d_in[0];
  const int*   ei_raw   = (const int*)d_in[1];
  const float* W1       = (const float*)d_in[2];
  const float* att_src1 = (const float*)d_in[3];
  const float* att_dst1 = (const float*)d_in[4];
  const float* b1       = (const float*)d_in[5];
  const float* W2       = (const float*)d_in[6];
  const float* att_src2 = (const float*)d_in[7];
  const float* att_dst2 = (const float*)d_in[8];
  const float* b2       = (const float*)d_in[9];
  const float* g1       = (const float*)d_in[10];
  const float* be1      = (const float*)d_in[11];
  const float* g2       = (const float*)d_in[12];
  const float* be2      = (const float*)d_in[13];
  const float* Wc1      = (const float*)d_in[14];
  const float* bc1      = (const float*)d_in[15];
  const float* Wc2      = (const float*)d_in[16];
  const float* bc2      = (const float*)d_in[17];
  float* out = (float*)d_out;

  char* ws = (char*)d_ws;
  size_t o = 0;
  unsigned short* h1b   = (unsigned short*)(ws + o); o += (size_t)N_NODES * F1 * 2;  // 40.96 MB
  unsigned short* out1b = (unsigned short*)(ws + o); o += (size_t)N_NODES * F1 * 2;  // 40.96 MB
  unsigned short* xb    = (unsigned short*)(ws + o); o += (size_t)N_NODES * DIN * 2; // 30.72 MB
  unsigned short* h2b   = (unsigned short*)(ws + o); o += (size_t)N_NODES * F2 * 2;  // 5.12 MB
  float* out2  = (float*)(ws + o); o += (size_t)N_NODES * F2 * 4;                    // 10.24 MB
  float* as1   = (float*)(ws + o); o += (size_t)N_NODES * H1 * 4;
  float* ad1   = (float*)(ws + o); o += (size_t)N_NODES * H1 * 4;
  float* as2   = (float*)(ws + o); o += (size_t)N_NODES * 4;
  float* ad2   = (float*)(ws + o); o += (size_t)N_NODES * 4;
  char*  zbase = ws + o;
  float* bnsum1 = (float*)(ws + o); o += F1 * 2 * 4;
  float* bnsum2 = (float*)(ws + o); o += F2 * 2 * 4;
  int*   deg    = (int*)(ws + o); o += (size_t)N_NODES * 4;
  size_t zbytes = (size_t)((ws + o) - zbase);
  int*   offv   = (int*)(ws + o); o += (size_t)(N_NODES + 4) * 4;
  int*   cursor = (int*)(ws + o); o += (size_t)N_NODES * 4;
  int*   elist  = (int*)(ws + o); o += (size_t)N_EDGES * 4;
  float* ss1    = (float*)(ws + o); o += F1 * 2 * 4;
  float* ss2    = (float*)(ws + o); o += F2 * 2 * 4;
  int*   ei32   = (int*)(ws + o); o += (size_t)2 * N_EDGES * 4;
  unsigned short* W1T = (unsigned short*)(ws + o); o += (size_t)F1 * DIN * 2;
  unsigned short* W2T = (unsigned short*)(ws + o); o += (size_t)F2 * F1 * 2;
  (void)ws_size; (void)in_sizes; (void)n_in; (void)out_size;

  hipMemsetAsync((void*)zbase, 0, zbytes, stream);

  // input conversions
  f2b_kernel<<<2048, 256, 0, stream>>>(x, xb, (size_t)N_NODES * DIN / 4);
  {
    dim3 g1d(F1 / 32, DIN / 32);
    transpose_b_kernel<<<g1d, 256, 0, stream>>>(W1, W1T, DIN, F1);
    dim3 g2d(F2 / 32, F1 / 32);
    transpose_b_kernel<<<g2d, 256, 0, stream>>>(W2, W2T, F1, F2);
  }

  // CSR build
  repack_hist_kernel<<<(2 * N_EDGES + 255) / 256, 256, 0, stream>>>(ei_raw, ei32, deg);
  scan_kernel<<<1, 1024, 0, stream>>>(deg, offv, cursor);
  scatter_kernel<<<(N_EDGES + 255) / 256, 256, 0, stream>>>(ei32, cursor, elist);

  // layer 1: h1 = x @ W1 (bf16 MFMA, fused att logits)
  {
    dim3 grid(F1 / GBN, (N_NODES + GBM - 1) / GBM);
    mfma_gemm_att_kernel<H1><<<grid, 256, 0, stream>>>(
        xb, W1T, h1b, att_src1, att_dst1, as1, ad1, N_NODES, F1, DIN);
  }
  gather1_kernel<<<N_NODES, 128, 0, stream>>>(h1b, as1, ad1, offv, elist, b1, out1b);
  {
    int rows = 79;
    int grid = (N_NODES + rows - 1) / rows;
    bnstats_bf16_kernel<<<grid, 256, 0, stream>>>(out1b, bnsum1, N_NODES, F1, rows);
  }
  bnfinal_kernel<<<(F1 + 255) / 256, 256, 0, stream>>>(bnsum1, g1, be1, ss1, F1);
  bnapply_bf16_kernel<<<2048, 256, 0, stream>>>(out1b, ss1, F1, (size_t)N_NODES * F1 / 4);

  // layer 2: h2 = out1b @ W2 (bf16 MFMA, fused att logits)
  {
    dim3 grid(F2 / GBN, (N_NODES + GBM - 1) / GBM);
    mfma_gemm_att_kernel<1><<<grid, 256, 0, stream>>>(
        out1b, W2T, h2b, att_src2, att_dst2, as2, ad2, N_NODES, F2, F1);
  }
  gather2_kernel<<<N_NODES, 64, 0, stream>>>(h2b, as2, ad2, offv, elist, b2, out2);
  {
    int rows = 79;
    int grid = (N_NODES + rows - 1) / rows;
    bnstats_kernel<1><<<grid, 128, 0, stream>>>(out2, bnsum2, N_NODES, F2, rows);
  }
  bnfinal_kernel<<<1, F2, 0, stream>>>(bnsum2, g2, be2, ss2, F2);

  // classifier (BN2 apply + ELU fused)
  cls_kernel<<<N_NODES, 64, 0, stream>>>(out2, ss2, Wc1, bc1, Wc2, bc2, out);
}

// Round 6
// 427.420 us; speedup vs baseline: 2.4628x; 1.0051x over previous
//
#include <hip/hip_runtime.h>
#include <hip/hip_bf16.h>
#include <math.h>

#define N_NODES 20000
#define N_EDGES 320000
#define DIN 768
#define F1 1024   // H1*C1
#define H1 8
#define C1 128
#define F2 128
#define NEG_SLOPE 0.2f
#define BN_EPS 1e-5f
#define RESCALE_THR 8.0f

typedef __attribute__((ext_vector_type(8))) __bf16 bf16x8;
typedef __attribute__((ext_vector_type(4))) float f32x4;

__device__ __forceinline__ float leaky(float x) { return x > 0.f ? x : NEG_SLOPE * x; }

__device__ __forceinline__ unsigned short f2bu(float x) {
  __hip_bfloat16 b = __float2bfloat16(x);
  return *(unsigned short*)&b;
}
__device__ __forceinline__ float b2f(unsigned short u) {
  return __uint_as_float(((unsigned)u) << 16);
}
__device__ __forceinline__ unsigned pack2(float lo, float hi) {
  return (unsigned)f2bu(lo) | ((unsigned)f2bu(hi) << 16);
}

__device__ __forceinline__ void async_copy16(void* lds, const void* g) {
  __builtin_amdgcn_global_load_lds(
      (const __attribute__((address_space(1))) unsigned int*)g,
      (__attribute__((address_space(3))) unsigned int*)lds, 16, 0, 0);
}

// ---------------- edge_index repack + dst histogram (fused) ----------------
__global__ void repack_hist_kernel(const int* raw, int* ei32, int* deg) {
  int is64 = (raw[1] == 0 && raw[3] == 0 && raw[5] == 0 && raw[7] == 0) ? 1 : 0;
  int e = blockIdx.x * blockDim.x + threadIdx.x;
  if (e < 2 * N_EDGES) {
    int v = is64 ? raw[2 * e] : raw[e];
    ei32[e] = v;
    if (e >= N_EDGES) atomicAdd(&deg[v], 1);   // dst half
  }
}

// single-block scan: 1024 threads x 20 nodes each, 2 barriers total
#define NPT 20
__global__ __launch_bounds__(1024) void scan_kernel(const int* __restrict__ deg,
                                                    int* __restrict__ off,
                                                    int* __restrict__ cursor) {
  __shared__ int wsum[16];
  int tid = threadIdx.x;
  int lane = tid & 63, wv = tid >> 6;
  int base = tid * NPT;
  int loc[NPT];
  int run = 0;
#pragma unroll
  for (int k = 0; k < NPT; ++k) {
    int i = base + k;
    int v = (i < N_NODES) ? deg[i] : 0;
    loc[k] = run;
    run += v;
  }
  int incl = run;
  for (int sh = 1; sh < 64; sh <<= 1) {
    int t = __shfl_up(incl, sh, 64);
    if (lane >= sh) incl += t;
  }
  if (lane == 63) wsum[wv] = incl;
  __syncthreads();
  if (wv == 0 && lane < 16) {
    int v = wsum[lane];
    for (int sh = 1; sh < 16; sh <<= 1) {
      int t = __shfl_up(v, sh, 16);
      if (lane >= sh) v += t;
    }
    wsum[lane] = v;
  }
  __syncthreads();
  int wbase = (wv > 0) ? wsum[wv - 1] : 0;
  int tbase = wbase + incl - run;
#pragma unroll
  for (int k = 0; k < NPT; ++k) {
    int i = base + k;
    if (i < N_NODES) {
      int o = tbase + loc[k];
      off[i] = o;
      cursor[i] = o;
    }
  }
  if (tid == 1023) off[N_NODES] = wbase + incl;
}

__global__ void scatter_kernel(const int* ei, int* cursor, int* elist) {
  int e = blockIdx.x * blockDim.x + threadIdx.x;
  if (e < N_EDGES) {
    int dst = ei[N_EDGES + e];
    int p = atomicAdd(&cursor[dst], 1);
    elist[p] = ei[e];
  }
}

// ---------------- fp32 -> bf16 convert ----------------
__global__ void f2b_kernel(const float* __restrict__ in, unsigned short* __restrict__ out,
                           size_t n4) {
  size_t i = (size_t)blockIdx.x * blockDim.x + threadIdx.x;
  size_t stride = (size_t)gridDim.x * blockDim.x;
  for (; i < n4; i += stride) {
    float4 v = ((const float4*)in)[i];
    ushort4 u;
    u.x = f2bu(v.x); u.y = f2bu(v.y); u.z = f2bu(v.z); u.w = f2bu(v.w);
    ((ushort4*)out)[i] = u;
  }
}

// ---------------- transpose + convert: W[K][N] fp32 -> WT[N][K] bf16 ----------------
__global__ void transpose_b_kernel(const float* __restrict__ W, unsigned short* __restrict__ WT,
                                   int K, int N) {
  __shared__ float t[32][33];
  int k0 = blockIdx.y * 32, n0 = blockIdx.x * 32;
  int tx = threadIdx.x & 31, ty = threadIdx.x >> 5;
  for (int i = 0; i < 32; i += 8)
    t[ty + i][tx] = W[(size_t)(k0 + ty + i) * N + n0 + tx];
  __syncthreads();
  for (int i = 0; i < 32; i += 8)
    WT[(size_t)(n0 + ty + i) * K + k0 + tx] = f2bu(t[tx][ty + i]);
}

// ---------------- bf16 MFMA GEMM + fused att-logit epilogue ----------------
#define GBM 128
#define GBN 128
#define GBK 64
template <int H>
__global__ __launch_bounds__(256) void mfma_gemm_att_kernel(
    const unsigned short* __restrict__ A,   // [M][K] bf16
    const unsigned short* __restrict__ BT,  // [N][K] bf16
    unsigned short* __restrict__ C,         // [M][N] bf16
    const float* __restrict__ att_src,      // [N]
    const float* __restrict__ att_dst,      // [N]
    float* __restrict__ as_out,             // [M][H]
    float* __restrict__ ad_out,             // [M][H]
    int M, int N, int K) {
  __shared__ __hip_bfloat16 As[GBM][GBK];
  __shared__ __hip_bfloat16 Bs[GBN][GBK];
  __shared__ float sred[128][2];
  __shared__ float dred[128][2];
  int tid = threadIdx.x;
  int lane = tid & 63, wid = tid >> 6;
  int wr = wid >> 1, wc = wid & 1;                // 2x2 wave grid, 64x64 out each
  int row0 = blockIdx.y * GBM, col0 = blockIdx.x * GBN;
  int head = blockIdx.x;                          // gridDim.x == H
  int l16 = lane & 15, l4 = lane >> 4;
  f32x4 acc[4][4] = {};
  for (int k0 = 0; k0 < K; k0 += GBK) {
#pragma unroll
    for (int j = 0; j < 4; ++j) {
      int c = j * 256 + tid;
      int r = c >> 3, kk = (c & 7) << 3;
      int ga = row0 + r; if (ga >= M) ga = M - 1;
      async_copy16(&As[r][kk], A + (size_t)ga * K + k0 + kk);
      async_copy16(&Bs[r][kk], BT + (size_t)(col0 + r) * K + k0 + kk);
    }
    __syncthreads();
#pragma unroll
    for (int ks = 0; ks < 2; ++ks) {
      bf16x8 af[4], bfr[4];
#pragma unroll
      for (int i = 0; i < 4; ++i)
        af[i] = *(const bf16x8*)&As[wr * 64 + i * 16 + l16][ks * 32 + l4 * 8];
#pragma unroll
      for (int j = 0; j < 4; ++j)
        bfr[j] = *(const bf16x8*)&Bs[wc * 64 + j * 16 + l16][ks * 32 + l4 * 8];
#pragma unroll
      for (int i = 0; i < 4; ++i)
#pragma unroll
        for (int j = 0; j < 4; ++j)
          acc[i][j] = __builtin_amdgcn_mfma_f32_16x16x32_bf16(af[i], bfr[j], acc[i][j], 0, 0, 0);
    }
    __syncthreads();
  }
  // ---- C store (bf16): col=lane&15, row=(lane>>4)*4+r ----
#pragma unroll
  for (int i = 0; i < 4; ++i) {
#pragma unroll
    for (int j = 0; j < 4; ++j) {
#pragma unroll
      for (int r = 0; r < 4; ++r) {
        int row = row0 + wr * 64 + i * 16 + l4 * 4 + r;
        int col = col0 + wc * 64 + j * 16 + l16;
        if (row < M) C[(size_t)row * N + col] = f2bu(acc[i][j][r]);
      }
    }
  }
  // ---- fused attention logits from fp32 accumulators ----
  float avs[4], avd[4];
#pragma unroll
  for (int j = 0; j < 4; ++j) {
    int col = col0 + wc * 64 + j * 16 + l16;
    avs[j] = att_src[col];
    avd[j] = att_dst[col];
  }
#pragma unroll
  for (int i = 0; i < 4; ++i) {
#pragma unroll
    for (int r = 0; r < 4; ++r) {
      float ps = 0.f, pd = 0.f;
#pragma unroll
      for (int j = 0; j < 4; ++j) { ps += acc[i][j][r] * avs[j]; pd += acc[i][j][r] * avd[j]; }
#pragma unroll
      for (int mk = 1; mk < 16; mk <<= 1) {
        ps += __shfl_xor(ps, mk, 64);
        pd += __shfl_xor(pd, mk, 64);
      }
      if (l16 == 0) {
        int lr = wr * 64 + i * 16 + l4 * 4 + r;
        sred[lr][wc] = ps;
        dred[lr][wc] = pd;
      }
    }
  }
  __syncthreads();
  if (tid < 128) {
    int row = row0 + tid;
    if (row < M) {
      as_out[(size_t)row * H + head] = sred[tid][0] + sred[tid][1];
      ad_out[(size_t)row * H + head] = dred[tid][0] + dred[tid][1];
    }
  }
}

// ---------------- gather layer 1: online softmax, chunk-4 double-buffered ----------------
// 8 row-loads + 2 logit chains in flight per wave; guards are wave-uniform.
#define G1_LOAD(i, rv, ev)                                                     \
  if ((i) < e) {                                                               \
    int ssrc = elist[(i)];                                                     \
    ev = leaky(as1[ssrc * H1 + head] + ad);                                    \
    rv = *(const uint4*)(h1 + (size_t)ssrc * F1 + tid * 8);                    \
  }
#define G1_CONSUME(u, el)                                                      \
  {                                                                            \
    float w;                                                                   \
    if (el > m + RESCALE_THR) {                                                \
      float rr = __expf(m - el);                                               \
      z *= rr;                                                                 \
      acc0 *= rr; acc1 *= rr; acc2 *= rr; acc3 *= rr;                          \
      acc4 *= rr; acc5 *= rr; acc6 *= rr; acc7 *= rr;                          \
      m = el; w = 1.f;                                                         \
    } else {                                                                   \
      w = __expf(el - m);                                                      \
    }                                                                          \
    z += w;                                                                    \
    acc0 += w * __uint_as_float(u.x << 16);                                    \
    acc1 += w * __uint_as_float(u.x & 0xffff0000u);                            \
    acc2 += w * __uint_as_float(u.y << 16);                                    \
    acc3 += w * __uint_as_float(u.y & 0xffff0000u);                            \
    acc4 += w * __uint_as_float(u.z << 16);                                    \
    acc5 += w * __uint_as_float(u.z & 0xffff0000u);                            \
    acc6 += w * __uint_as_float(u.w << 16);                                    \
    acc7 += w * __uint_as_float(u.w & 0xffff0000u);                            \
  }

__global__ __launch_bounds__(128) void gather1_kernel(const unsigned short* __restrict__ h1,
                                                      const float* __restrict__ as1,
                                                      const float* __restrict__ ad1,
                                                      const int* __restrict__ off,
                                                      const int* __restrict__ elist,
                                                      const float* __restrict__ b1,
                                                      unsigned short* __restrict__ out1) {
  int node = blockIdx.x;
  int tid = threadIdx.x;           // 128 threads, 8 channels each
  int head = tid >> 4;
  const float ad = ad1[node * H1 + head];
  int s = off[node], e = off[node + 1];
  float m = leaky(as1[node * H1 + head] + ad);
  float z = 1.f;
  float acc0, acc1, acc2, acc3, acc4, acc5, acc6, acc7;
  {
    uint4 u = *(const uint4*)(h1 + (size_t)node * F1 + tid * 8);
    acc0 = __uint_as_float(u.x << 16); acc1 = __uint_as_float(u.x & 0xffff0000u);
    acc2 = __uint_as_float(u.y << 16); acc3 = __uint_as_float(u.y & 0xffff0000u);
    acc4 = __uint_as_float(u.z << 16); acc5 = __uint_as_float(u.z & 0xffff0000u);
    acc6 = __uint_as_float(u.w << 16); acc7 = __uint_as_float(u.w & 0xffff0000u);
  }
  uint4 ra0 = {}, ra1 = {}, ra2 = {}, ra3 = {};
  float ea0 = 0.f, ea1 = 0.f, ea2 = 0.f, ea3 = 0.f;
  G1_LOAD(s + 0, ra0, ea0)
  G1_LOAD(s + 1, ra1, ea1)
  G1_LOAD(s + 2, ra2, ea2)
  G1_LOAD(s + 3, ra3, ea3)
  for (int base = s; base < e; base += 4) {
    uint4 rb0 = {}, rb1 = {}, rb2 = {}, rb3 = {};
    float eb0 = 0.f, eb1 = 0.f, eb2 = 0.f, eb3 = 0.f;
    int nb = base + 4;
    G1_LOAD(nb + 0, rb0, eb0)
    G1_LOAD(nb + 1, rb1, eb1)
    G1_LOAD(nb + 2, rb2, eb2)
    G1_LOAD(nb + 3, rb3, eb3)
    G1_CONSUME(ra0, ea0)
    if (base + 1 < e) G1_CONSUME(ra1, ea1)
    if (base + 2 < e) G1_CONSUME(ra2, ea2)
    if (base + 3 < e) G1_CONSUME(ra3, ea3)
    ra0 = rb0; ra1 = rb1; ra2 = rb2; ra3 = rb3;
    ea0 = eb0; ea1 = eb1; ea2 = eb2; ea3 = eb3;
  }
  float inv = 1.f / z;
  const float4 bv0 = *(const float4*)(b1 + tid * 8);
  const float4 bv1 = *(const float4*)(b1 + tid * 8 + 4);
  uint4 o;
  o.x = pack2(acc0 * inv + bv0.x, acc1 * inv + bv0.y);
  o.y = pack2(acc2 * inv + bv0.z, acc3 * inv + bv0.w);
  o.z = pack2(acc4 * inv + bv1.x, acc5 * inv + bv1.y);
  o.w = pack2(acc6 * inv + bv1.z, acc7 * inv + bv1.w);
  *(uint4*)(out1 + (size_t)node * F1 + tid * 8) = o;
}

// ---------------- BN statistics, bf16 input ----------------
__global__ void bnstats_bf16_kernel(const unsigned short* __restrict__ x,
                                    float* __restrict__ sums,
                                    int nrows, int F, int rowsPerBlock) {
  int tid = threadIdx.x;
  int c = tid * 4;
  int r0 = blockIdx.x * rowsPerBlock;
  int rend = min(r0 + rowsPerBlock, nrows);
  float s0 = 0.f, s1 = 0.f, s2 = 0.f, s3 = 0.f;
  float q0 = 0.f, q1 = 0.f, q2 = 0.f, q3 = 0.f;
  for (int r = r0; r < rend; ++r) {
    ushort4 u = *(const ushort4*)(x + (size_t)r * F + c);
    float v0 = b2f(u.x), v1 = b2f(u.y), v2 = b2f(u.z), v3 = b2f(u.w);
    s0 += v0; s1 += v1; s2 += v2; s3 += v3;
    q0 += v0 * v0; q1 += v1 * v1; q2 += v2 * v2; q3 += v3 * v3;
  }
  atomicAdd(&sums[c + 0], s0); atomicAdd(&sums[c + 1], s1);
  atomicAdd(&sums[c + 2], s2); atomicAdd(&sums[c + 3], s3);
  atomicAdd(&sums[F + c + 0], q0); atomicAdd(&sums[F + c + 1], q1);
  atomicAdd(&sums[F + c + 2], q2); atomicAdd(&sums[F + c + 3], q3);
}

// fp32-input variant (layer 2, small)
template <int CPT>
__global__ void bnstats_kernel(const float* __restrict__ x, float* __restrict__ sums,
                               int nrows, int F, int rowsPerBlock) {
  int tid = threadIdx.x;
  int r0 = blockIdx.x * rowsPerBlock;
  int rend = min(r0 + rowsPerBlock, nrows);
  float s[CPT], q[CPT];
#pragma unroll
  for (int k = 0; k < CPT; ++k) { s[k] = 0.f; q[k] = 0.f; }
  for (int r = r0; r < rend; ++r) {
    const float* row = x + (size_t)r * F;
#pragma unroll
    for (int k = 0; k < CPT; ++k) {
      float v = row[tid + k * blockDim.x];
      s[k] += v; q[k] += v * v;
    }
  }
#pragma unroll
  for (int k = 0; k < CPT; ++k) {
    atomicAdd(&sums[tid + k * blockDim.x], s[k]);
    atomicAdd(&sums[F + tid + k * blockDim.x], q[k]);
  }
}

__global__ void bnfinal_kernel(const float* __restrict__ sums, const float* __restrict__ g,
                               const float* __restrict__ be, float* __restrict__ ss, int F) {
  int c = blockIdx.x * blockDim.x + threadIdx.x;
  if (c < F) {
    float mu = sums[c] * (1.f / N_NODES);
    float var = sums[F + c] * (1.f / N_NODES) - mu * mu;
    float sc = g[c] * rsqrtf(var + BN_EPS);
    ss[c] = sc;
    ss[F + c] = be[c] - mu * sc;
  }
}

// BN apply + ELU, bf16 in-place (layer 1, feeds GEMM2)
__global__ void bnapply_bf16_kernel(unsigned short* __restrict__ x, const float* __restrict__ ss,
                                    int F, size_t total4) {
  size_t i = (size_t)blockIdx.x * blockDim.x + threadIdx.x;
  size_t stride = (size_t)gridDim.x * blockDim.x;
  for (; i < total4; i += stride) {
    int c = (int)((i * 4) & (size_t)(F - 1));
    ushort4 u = ((ushort4*)x)[i];
    float v0 = b2f(u.x) * ss[c + 0] + ss[F + c + 0];
    float v1 = b2f(u.y) * ss[c + 1] + ss[F + c + 1];
    float v2 = b2f(u.z) * ss[c + 2] + ss[F + c + 2];
    float v3 = b2f(u.w) * ss[c + 3] + ss[F + c + 3];
    v0 = v0 > 0.f ? v0 : expm1f(v0);
    v1 = v1 > 0.f ? v1 : expm1f(v1);
    v2 = v2 > 0.f ? v2 : expm1f(v2);
    v3 = v3 > 0.f ? v3 : expm1f(v3);
    u.x = f2bu(v0); u.y = f2bu(v1); u.z = f2bu(v2); u.w = f2bu(v3);
    ((ushort4*)x)[i] = u;
  }
}

// ---------------- gather layer 2: online softmax, chunk-4 double-buffered ----------------
#define G2_LOAD(i, rv, ev)                                                     \
  if ((i) < e) {                                                               \
    int ssrc = elist[(i)];                                                     \
    ev = leaky(as2[ssrc] + ad);                                                \
    rv = *(const unsigned*)(h2 + (size_t)ssrc * F2 + tid * 2);                 \
  }
#define G2_CONSUME(u, el)                                                      \
  {                                                                            \
    float w;                                                                   \
    if (el > m + RESCALE_THR) {                                                \
      float rr = __expf(m - el);                                               \
      z *= rr; a0 *= rr; a1 *= rr;                                             \
      m = el; w = 1.f;                                                         \
    } else {                                                                   \
      w = __expf(el - m);                                                      \
    }                                                                          \
    z += w;                                                                    \
    a0 += w * __uint_as_float(u << 16);                                        \
    a1 += w * __uint_as_float(u & 0xffff0000u);                                \
  }

__global__ __launch_bounds__(64) void gather2_kernel(const unsigned short* __restrict__ h2,
                                                     const float* __restrict__ as2,
                                                     const float* __restrict__ ad2,
                                                     const int* __restrict__ off,
                                                     const int* __restrict__ elist,
                                                     const float* __restrict__ b2,
                                                     float* __restrict__ out2) {
  int node = blockIdx.x;
  int tid = threadIdx.x;          // 64, 2 channels each
  const float ad = ad2[node];
  int s = off[node], e = off[node + 1];
  float m = leaky(as2[node] + ad);
  float z = 1.f;
  float a0, a1;
  {
    unsigned u = *(const unsigned*)(h2 + (size_t)node * F2 + tid * 2);
    a0 = __uint_as_float(u << 16); a1 = __uint_as_float(u & 0xffff0000u);
  }
  unsigned ra0 = 0, ra1 = 0, ra2 = 0, ra3 = 0;
  float ea0 = 0.f, ea1 = 0.f, ea2 = 0.f, ea3 = 0.f;
  G2_LOAD(s + 0, ra0, ea0)
  G2_LOAD(s + 1, ra1, ea1)
  G2_LOAD(s + 2, ra2, ea2)
  G2_LOAD(s + 3, ra3, ea3)
  for (int base = s; base < e; base += 4) {
    unsigned rb0 = 0, rb1 = 0, rb2 = 0, rb3 = 0;
    float eb0 = 0.f, eb1 = 0.f, eb2 = 0.f, eb3 = 0.f;
    int nb = base + 4;
    G2_LOAD(nb + 0, rb0, eb0)
    G2_LOAD(nb + 1, rb1, eb1)
    G2_LOAD(nb + 2, rb2, eb2)
    G2_LOAD(nb + 3, rb3, eb3)
    G2_CONSUME(ra0, ea0)
    if (base + 1 < e) G2_CONSUME(ra1, ea1)
    if (base + 2 < e) G2_CONSUME(ra2, ea2)
    if (base + 3 < e) G2_CONSUME(ra3, ea3)
    ra0 = rb0; ra1 = rb1; ra2 = rb2; ra3 = rb3;
    ea0 = eb0; ea1 = eb1; ea2 = eb2; ea3 = eb3;
  }
  float inv = 1.f / z;
  float2 o = make_float2(a0 * inv + b2[tid * 2 + 0], a1 * inv + b2[tid * 2 + 1]);
  *(float2*)(out2 + (size_t)node * F2 + tid * 2) = o;
}

// ---------------- classifier head (fused BN2 apply + ELU) ----------------
__global__ __launch_bounds__(64) void cls_kernel(const float* __restrict__ h,
                                                 const float* __restrict__ ss2,
                                                 const float* __restrict__ Wc1,
                                                 const float* __restrict__ bc1,
                                                 const float* __restrict__ Wc2,
                                                 const float* __restrict__ bc2,
                                                 float* __restrict__ out) {
  __shared__ float hl[128];
  int node = blockIdx.x;
  int tid = threadIdx.x;          // 64
  {
    float v = h[(size_t)node * F2 + tid] * ss2[tid] + ss2[F2 + tid];
    v = v > 0.f ? v : expm1f(v);
    hl[tid] = v;
    float v2 = h[(size_t)node * F2 + 64 + tid] * ss2[64 + tid] + ss2[F2 + 64 + tid];
    v2 = v2 > 0.f ? v2 : expm1f(v2);
    hl[tid + 64] = v2;
  }
  __syncthreads();
  float acc = bc1[tid];
#pragma unroll
  for (int k = 0; k < 128; ++k) acc += hl[k] * Wc1[k * 64 + tid];
  acc = fmaxf(acc, 0.f);
  float2 w = *(const float2*)(Wc2 + tid * 2);
  float o0 = acc * w.x, o1 = acc * w.y;
  for (int sh = 32; sh >= 1; sh >>= 1) {
    o0 += __shfl_down(o0, sh, 64);
    o1 += __shfl_down(o1, sh, 64);
  }
  if (tid == 0) {
    out[node * 2 + 0] = o0 + bc2[0];
    out[node * 2 + 1] = o1 + bc2[1];
  }
}

extern "C" void kernel_launch(void* const* d_in, const int* in_sizes, int n_in,
                              void* d_out, int out_size, void* d_ws, size_t ws_size,
                              hipStream_t stream) {
  const float* x        = (const float*)d_in[0];
  const int*   ei_raw   = (const int*)d_in[1];
  const float* W1       = (const float*)d_in[2];
  const float* att_src1 = (const float*)d_in[3];
  const float* att_dst1 = (const float*)d_in[4];
  const float* b1       = (const float*)d_in[5];
  const float* W2       = (const float*)d_in[6];
  const float* att_src2 = (const float*)d_in[7];
  const float* att_dst2 = (const float*)d_in[8];
  const float* b2       = (const float*)d_in[9];
  const float* g1       = (const float*)d_in[10];
  const float* be1      = (const float*)d_in[11];
  const float* g2       = (const float*)d_in[12];
  const float* be2      = (const float*)d_in[13];
  const float* Wc1      = (const float*)d_in[14];
  const float* bc1      = (const float*)d_in[15];
  const float* Wc2      = (const float*)d_in[16];
  const float* bc2      = (const float*)d_in[17];
  float* out = (float*)d_out;

  char* ws = (char*)d_ws;
  size_t o = 0;
  unsigned short* h1b   = (unsigned short*)(ws + o); o += (size_t)N_NODES * F1 * 2;  // 40.96 MB
  unsigned short* out1b = (unsigned short*)(ws + o); o += (size_t)N_NODES * F1 * 2;  // 40.96 MB
  unsigned short* xb    = (unsigned short*)(ws + o); o += (size_t)N_NODES * DIN * 2; // 30.72 MB
  unsigned short* h2b   = (unsigned short*)(ws + o); o += (size_t)N_NODES * F2 * 2;  // 5.12 MB
  float* out2  = (float*)(ws + o); o += (size_t)N_NODES * F2 * 4;                    // 10.24 MB
  float* as1   = (float*)(ws + o); o += (size_t)N_NODES * H1 * 4;
  float* ad1   = (float*)(ws + o); o += (size_t)N_NODES * H1 * 4;
  float* as2   = (float*)(ws + o); o += (size_t)N_NODES * 4;
  float* ad2   = (float*)(ws + o); o += (size_t)N_NODES * 4;
  char*  zbase = ws + o;
  float* bnsum1 = (float*)(ws + o); o += F1 * 2 * 4;
  float* bnsum2 = (float*)(ws + o); o += F2 * 2 * 4;
  int*   deg    = (int*)(ws + o); o += (size_t)N_NODES * 4;
  size_t zbytes = (size_t)((ws + o) - zbase);
  int*   offv   = (int*)(ws + o); o += (size_t)(N_NODES + 4) * 4;
  int*   cursor = (int*)(ws + o); o += (size_t)N_NODES * 4;
  int*   elist  = (int*)(ws + o); o += (size_t)N_EDGES * 4;
  float* ss1    = (float*)(ws + o); o += F1 * 2 * 4;
  float* ss2    = (float*)(ws + o); o += F2 * 2 * 4;
  int*   ei32   = (int*)(ws + o); o += (size_t)2 * N_EDGES * 4;
  unsigned short* W1T = (unsigned short*)(ws + o); o += (size_t)F1 * DIN * 2;
  unsigned short* W2T = (unsigned short*)(ws + o); o += (size_t)F2 * F1 * 2;
  (void)ws_size; (void)in_sizes; (void)n_in; (void)out_size;

  hipMemsetAsync((void*)zbase, 0, zbytes, stream);

  // input conversions
  f2b_kernel<<<2048, 256, 0, stream>>>(x, xb, (size_t)N_NODES * DIN / 4);
  {
    dim3 g1d(F1 / 32, DIN / 32);
    transpose_b_kernel<<<g1d, 256, 0, stream>>>(W1, W1T, DIN, F1);
    dim3 g2d(F2 / 32, F1 / 32);
    transpose_b_kernel<<<g2d, 256, 0, stream>>>(W2, W2T, F1, F2);
  }

  // CSR build
  repack_hist_kernel<<<(2 * N_EDGES + 255) / 256, 256, 0, stream>>>(ei_raw, ei32, deg);
  scan_kernel<<<1, 1024, 0, stream>>>(deg, offv, cursor);
  scatter_kernel<<<(N_EDGES + 255) / 256, 256, 0, stream>>>(ei32, cursor, elist);

  // layer 1: h1 = x @ W1 (bf16 MFMA, fused att logits)
  {
    dim3 grid(F1 / GBN, (N_NODES + GBM - 1) / GBM);
    mfma_gemm_att_kernel<H1><<<grid, 256, 0, stream>>>(
        xb, W1T, h1b, att_src1, att_dst1, as1, ad1, N_NODES, F1, DIN);
  }
  gather1_kernel<<<N_NODES, 128, 0, stream>>>(h1b, as1, ad1, offv, elist, b1, out1b);
  {
    int rows = 79;
    int grid = (N_NODES + rows - 1) / rows;
    bnstats_bf16_kernel<<<grid, 256, 0, stream>>>(out1b, bnsum1, N_NODES, F1, rows);
  }
  bnfinal_kernel<<<(F1 + 255) / 256, 256, 0, stream>>>(bnsum1, g1, be1, ss1, F1);
  bnapply_bf16_kernel<<<2048, 256, 0, stream>>>(out1b, ss1, F1, (size_t)N_NODES * F1 / 4);

  // layer 2: h2 = out1b @ W2 (bf16 MFMA, fused att logits)
  {
    dim3 grid(F2 / GBN, (N_NODES + GBM - 1) / GBM);
    mfma_gemm_att_kernel<1><<<grid, 256, 0, stream>>>(
        out1b, W2T, h2b, att_src2, att_dst2, as2, ad2, N_NODES, F2, F1);
  }
  gather2_kernel<<<N_NODES, 64, 0, stream>>>(h2b, as2, ad2, offv, elist, b2, out2);
  {
    int rows = 79;
    int grid = (N_NODES + rows - 1) / rows;
    bnstats_kernel<1><<<grid, 128, 0, stream>>>(out2, bnsum2, N_NODES, F2, rows);
  }
  bnfinal_kernel<<<1, F2, 0, stream>>>(bnsum2, g2, be2, ss2, F2);

  // classifier (BN2 apply + ELU fused)
  cls_kernel<<<N_NODES, 64, 0, stream>>>(out2, ss2, Wc1, bc1, Wc2, bc2, out);
}

// Round 7
// 427.213 us; speedup vs baseline: 2.4640x; 1.0005x over previous
//
#include <hip/hip_runtime.h>
#include <hip/hip_bf16.h>
#include <math.h>

#define N_NODES 20000
#define N_EDGES 320000
#define DIN 768
#define F1 1024   // H1*C1
#define H1 8
#define C1 128
#define F2 128
#define NEG_SLOPE 0.2f
#define BN_EPS 1e-5f
#define RESCALE_THR 8.0f

typedef __attribute__((ext_vector_type(8))) __bf16 bf16x8;
typedef __attribute__((ext_vector_type(4))) float f32x4;

__device__ __forceinline__ float leaky(float x) { return x > 0.f ? x : NEG_SLOPE * x; }

__device__ __forceinline__ unsigned short f2bu(float x) {
  __hip_bfloat16 b = __float2bfloat16(x);
  return *(unsigned short*)&b;
}
__device__ __forceinline__ float b2f(unsigned short u) {
  return __uint_as_float(((unsigned)u) << 16);
}
__device__ __forceinline__ unsigned pack2(float lo, float hi) {
  return (unsigned)f2bu(lo) | ((unsigned)f2bu(hi) << 16);
}

__device__ __forceinline__ void async_copy16(void* lds, const void* g) {
  __builtin_amdgcn_global_load_lds(
      (const __attribute__((address_space(1))) unsigned int*)g,
      (__attribute__((address_space(3))) unsigned int*)lds, 16, 0, 0);
}

// ---------------- edge_index repack + dst histogram (fused) ----------------
__global__ void repack_hist_kernel(const int* raw, int* ei32, int* deg) {
  int is64 = (raw[1] == 0 && raw[3] == 0 && raw[5] == 0 && raw[7] == 0) ? 1 : 0;
  int e = blockIdx.x * blockDim.x + threadIdx.x;
  if (e < 2 * N_EDGES) {
    int v = is64 ? raw[2 * e] : raw[e];
    ei32[e] = v;
    if (e >= N_EDGES) atomicAdd(&deg[v], 1);   // dst half
  }
}

// single-block scan: 1024 threads x 20 nodes each, 2 barriers total
#define NPT 20
__global__ __launch_bounds__(1024) void scan_kernel(const int* __restrict__ deg,
                                                    int* __restrict__ off,
                                                    int* __restrict__ cursor) {
  __shared__ int wsum[16];
  int tid = threadIdx.x;
  int lane = tid & 63, wv = tid >> 6;
  int base = tid * NPT;
  int loc[NPT];
  int run = 0;
#pragma unroll
  for (int k = 0; k < NPT; ++k) {
    int i = base + k;
    int v = (i < N_NODES) ? deg[i] : 0;
    loc[k] = run;
    run += v;
  }
  int incl = run;
  for (int sh = 1; sh < 64; sh <<= 1) {
    int t = __shfl_up(incl, sh, 64);
    if (lane >= sh) incl += t;
  }
  if (lane == 63) wsum[wv] = incl;
  __syncthreads();
  if (wv == 0 && lane < 16) {
    int v = wsum[lane];
    for (int sh = 1; sh < 16; sh <<= 1) {
      int t = __shfl_up(v, sh, 16);
      if (lane >= sh) v += t;
    }
    wsum[lane] = v;
  }
  __syncthreads();
  int wbase = (wv > 0) ? wsum[wv - 1] : 0;
  int tbase = wbase + incl - run;
#pragma unroll
  for (int k = 0; k < NPT; ++k) {
    int i = base + k;
    if (i < N_NODES) {
      int o = tbase + loc[k];
      off[i] = o;
      cursor[i] = o;
    }
  }
  if (tid == 1023) off[N_NODES] = wbase + incl;
}

__global__ void scatter_kernel(const int* ei, int* cursor, int* elist) {
  int e = blockIdx.x * blockDim.x + threadIdx.x;
  if (e < N_EDGES) {
    int dst = ei[N_EDGES + e];
    int p = atomicAdd(&cursor[dst], 1);
    elist[p] = ei[e];
  }
}

// ---------------- fp32 -> bf16 convert ----------------
__global__ void f2b_kernel(const float* __restrict__ in, unsigned short* __restrict__ out,
                           size_t n4) {
  size_t i = (size_t)blockIdx.x * blockDim.x + threadIdx.x;
  size_t stride = (size_t)gridDim.x * blockDim.x;
  for (; i < n4; i += stride) {
    float4 v = ((const float4*)in)[i];
    ushort4 u;
    u.x = f2bu(v.x); u.y = f2bu(v.y); u.z = f2bu(v.z); u.w = f2bu(v.w);
    ((ushort4*)out)[i] = u;
  }
}

// ---------------- transpose + convert: W[K][N] fp32 -> WT[N][K] bf16 ----------------
__global__ void transpose_b_kernel(const float* __restrict__ W, unsigned short* __restrict__ WT,
                                   int K, int N) {
  __shared__ float t[32][33];
  int k0 = blockIdx.y * 32, n0 = blockIdx.x * 32;
  int tx = threadIdx.x & 31, ty = threadIdx.x >> 5;
  for (int i = 0; i < 32; i += 8)
    t[ty + i][tx] = W[(size_t)(k0 + ty + i) * N + n0 + tx];
  __syncthreads();
  for (int i = 0; i < 32; i += 8)
    WT[(size_t)(n0 + ty + i) * K + k0 + tx] = f2bu(t[tx][ty + i]);
}

// ---------------- bf16 MFMA GEMM + fused att-logit epilogue ----------------
// SWZ=1: 1D grid, XCD panel-affinity swizzle — all 8 col-tiles of row-panel p
// land on XCD p%8 (id = (p&7) + 8*c + 64*(p>>3)), so each A-panel is fetched
// into exactly one per-XCD L2 instead of all 8.
#define GBM 128
#define GBN 128
#define GBK 64
template <int H, int SWZ>
__global__ __launch_bounds__(256) void mfma_gemm_att_kernel(
    const unsigned short* __restrict__ A,   // [M][K] bf16
    const unsigned short* __restrict__ BT,  // [N][K] bf16
    unsigned short* __restrict__ C,         // [M][N] bf16
    const float* __restrict__ att_src,      // [N]
    const float* __restrict__ att_dst,      // [N]
    float* __restrict__ as_out,             // [M][H]
    float* __restrict__ ad_out,             // [M][H]
    int M, int N, int K) {
  __shared__ __hip_bfloat16 As[GBM][GBK];
  __shared__ __hip_bfloat16 Bs[GBN][GBK];
  __shared__ float sred[128][2];
  __shared__ float dred[128][2];
  int bx, by;
  if (SWZ) {
    int bid = blockIdx.x;
    int pl = bid & 7, c = (bid >> 3) & 7, ph = bid >> 6;
    int p = ph * 8 + pl;
    if (p * GBM >= M) return;
    by = p; bx = c;
  } else {
    bx = blockIdx.x; by = blockIdx.y;
  }
  int tid = threadIdx.x;
  int lane = tid & 63, wid = tid >> 6;
  int wr = wid >> 1, wc = wid & 1;                // 2x2 wave grid, 64x64 out each
  int row0 = by * GBM, col0 = bx * GBN;
  int head = bx;                                  // col-tile == head (H tiles)
  int l16 = lane & 15, l4 = lane >> 4;
  f32x4 acc[4][4] = {};
  for (int k0 = 0; k0 < K; k0 += GBK) {
#pragma unroll
    for (int j = 0; j < 4; ++j) {
      int c = j * 256 + tid;
      int r = c >> 3, kk = (c & 7) << 3;
      int ga = row0 + r; if (ga >= M) ga = M - 1;
      async_copy16(&As[r][kk], A + (size_t)ga * K + k0 + kk);
      async_copy16(&Bs[r][kk], BT + (size_t)(col0 + r) * K + k0 + kk);
    }
    __syncthreads();
#pragma unroll
    for (int ks = 0; ks < 2; ++ks) {
      bf16x8 af[4], bfr[4];
#pragma unroll
      for (int i = 0; i < 4; ++i)
        af[i] = *(const bf16x8*)&As[wr * 64 + i * 16 + l16][ks * 32 + l4 * 8];
#pragma unroll
      for (int j = 0; j < 4; ++j)
        bfr[j] = *(const bf16x8*)&Bs[wc * 64 + j * 16 + l16][ks * 32 + l4 * 8];
#pragma unroll
      for (int i = 0; i < 4; ++i)
#pragma unroll
        for (int j = 0; j < 4; ++j)
          acc[i][j] = __builtin_amdgcn_mfma_f32_16x16x32_bf16(af[i], bfr[j], acc[i][j], 0, 0, 0);
    }
    __syncthreads();
  }
  // ---- C store (bf16): col=lane&15, row=(lane>>4)*4+r ----
#pragma unroll
  for (int i = 0; i < 4; ++i) {
#pragma unroll
    for (int j = 0; j < 4; ++j) {
#pragma unroll
      for (int r = 0; r < 4; ++r) {
        int row = row0 + wr * 64 + i * 16 + l4 * 4 + r;
        int col = col0 + wc * 64 + j * 16 + l16;
        if (row < M) C[(size_t)row * N + col] = f2bu(acc[i][j][r]);
      }
    }
  }
  // ---- fused attention logits from fp32 accumulators ----
  float avs[4], avd[4];
#pragma unroll
  for (int j = 0; j < 4; ++j) {
    int col = col0 + wc * 64 + j * 16 + l16;
    avs[j] = att_src[col];
    avd[j] = att_dst[col];
  }
#pragma unroll
  for (int i = 0; i < 4; ++i) {
#pragma unroll
    for (int r = 0; r < 4; ++r) {
      float ps = 0.f, pd = 0.f;
#pragma unroll
      for (int j = 0; j < 4; ++j) { ps += acc[i][j][r] * avs[j]; pd += acc[i][j][r] * avd[j]; }
#pragma unroll
      for (int mk = 1; mk < 16; mk <<= 1) {
        ps += __shfl_xor(ps, mk, 64);
        pd += __shfl_xor(pd, mk, 64);
      }
      if (l16 == 0) {
        int lr = wr * 64 + i * 16 + l4 * 4 + r;
        sred[lr][wc] = ps;
        dred[lr][wc] = pd;
      }
    }
  }
  __syncthreads();
  if (tid < 128) {
    int row = row0 + tid;
    if (row < M) {
      as_out[(size_t)row * H + head] = sred[tid][0] + sred[tid][1];
      ad_out[(size_t)row * H + head] = dred[tid][0] + dred[tid][1];
    }
  }
}

// ---------------- gather layer 1: online softmax, chunk-4 double-buffered ----------------
#define G1_LOAD(i, rv, ev)                                                     \
  if ((i) < e) {                                                               \
    int ssrc = elist[(i)];                                                     \
    ev = leaky(as1[ssrc * H1 + head] + ad);                                    \
    rv = *(const uint4*)(h1 + (size_t)ssrc * F1 + tid * 8);                    \
  }
#define G1_CONSUME(u, el)                                                      \
  {                                                                            \
    float w;                                                                   \
    if (el > m + RESCALE_THR) {                                                \
      float rr = __expf(m - el);                                               \
      z *= rr;                                                                 \
      acc0 *= rr; acc1 *= rr; acc2 *= rr; acc3 *= rr;                          \
      acc4 *= rr; acc5 *= rr; acc6 *= rr; acc7 *= rr;                          \
      m = el; w = 1.f;                                                         \
    } else {                                                                   \
      w = __expf(el - m);                                                      \
    }                                                                          \
    z += w;                                                                    \
    acc0 += w * __uint_as_float(u.x << 16);                                    \
    acc1 += w * __uint_as_float(u.x & 0xffff0000u);                            \
    acc2 += w * __uint_as_float(u.y << 16);                                    \
    acc3 += w * __uint_as_float(u.y & 0xffff0000u);                            \
    acc4 += w * __uint_as_float(u.z << 16);                                    \
    acc5 += w * __uint_as_float(u.z & 0xffff0000u);                            \
    acc6 += w * __uint_as_float(u.w << 16);                                    \
    acc7 += w * __uint_as_float(u.w & 0xffff0000u);                            \
  }

__global__ __launch_bounds__(128) void gather1_kernel(const unsigned short* __restrict__ h1,
                                                      const float* __restrict__ as1,
                                                      const float* __restrict__ ad1,
                                                      const int* __restrict__ off,
                                                      const int* __restrict__ elist,
                                                      const float* __restrict__ b1,
                                                      unsigned short* __restrict__ out1) {
  int node = blockIdx.x;
  int tid = threadIdx.x;           // 128 threads, 8 channels each
  int head = tid >> 4;
  const float ad = ad1[node * H1 + head];
  int s = off[node], e = off[node + 1];
  float m = leaky(as1[node * H1 + head] + ad);
  float z = 1.f;
  float acc0, acc1, acc2, acc3, acc4, acc5, acc6, acc7;
  {
    uint4 u = *(const uint4*)(h1 + (size_t)node * F1 + tid * 8);
    acc0 = __uint_as_float(u.x << 16); acc1 = __uint_as_float(u.x & 0xffff0000u);
    acc2 = __uint_as_float(u.y << 16); acc3 = __uint_as_float(u.y & 0xffff0000u);
    acc4 = __uint_as_float(u.z << 16); acc5 = __uint_as_float(u.z & 0xffff0000u);
    acc6 = __uint_as_float(u.w << 16); acc7 = __uint_as_float(u.w & 0xffff0000u);
  }
  uint4 ra0 = {}, ra1 = {}, ra2 = {}, ra3 = {};
  float ea0 = 0.f, ea1 = 0.f, ea2 = 0.f, ea3 = 0.f;
  G1_LOAD(s + 0, ra0, ea0)
  G1_LOAD(s + 1, ra1, ea1)
  G1_LOAD(s + 2, ra2, ea2)
  G1_LOAD(s + 3, ra3, ea3)
  for (int base = s; base < e; base += 4) {
    uint4 rb0 = {}, rb1 = {}, rb2 = {}, rb3 = {};
    float eb0 = 0.f, eb1 = 0.f, eb2 = 0.f, eb3 = 0.f;
    int nb = base + 4;
    G1_LOAD(nb + 0, rb0, eb0)
    G1_LOAD(nb + 1, rb1, eb1)
    G1_LOAD(nb + 2, rb2, eb2)
    G1_LOAD(nb + 3, rb3, eb3)
    G1_CONSUME(ra0, ea0)
    if (base + 1 < e) G1_CONSUME(ra1, ea1)
    if (base + 2 < e) G1_CONSUME(ra2, ea2)
    if (base + 3 < e) G1_CONSUME(ra3, ea3)
    ra0 = rb0; ra1 = rb1; ra2 = rb2; ra3 = rb3;
    ea0 = eb0; ea1 = eb1; ea2 = eb2; ea3 = eb3;
  }
  float inv = 1.f / z;
  const float4 bv0 = *(const float4*)(b1 + tid * 8);
  const float4 bv1 = *(const float4*)(b1 + tid * 8 + 4);
  uint4 o;
  o.x = pack2(acc0 * inv + bv0.x, acc1 * inv + bv0.y);
  o.y = pack2(acc2 * inv + bv0.z, acc3 * inv + bv0.w);
  o.z = pack2(acc4 * inv + bv1.x, acc5 * inv + bv1.y);
  o.w = pack2(acc6 * inv + bv1.z, acc7 * inv + bv1.w);
  *(uint4*)(out1 + (size_t)node * F1 + tid * 8) = o;
}

// ---------------- BN statistics, bf16 input ----------------
__global__ void bnstats_bf16_kernel(const unsigned short* __restrict__ x,
                                    float* __restrict__ sums,
                                    int nrows, int F, int rowsPerBlock) {
  int tid = threadIdx.x;
  int c = tid * 4;
  int r0 = blockIdx.x * rowsPerBlock;
  int rend = min(r0 + rowsPerBlock, nrows);
  float s0 = 0.f, s1 = 0.f, s2 = 0.f, s3 = 0.f;
  float q0 = 0.f, q1 = 0.f, q2 = 0.f, q3 = 0.f;
  for (int r = r0; r < rend; ++r) {
    ushort4 u = *(const ushort4*)(x + (size_t)r * F + c);
    float v0 = b2f(u.x), v1 = b2f(u.y), v2 = b2f(u.z), v3 = b2f(u.w);
    s0 += v0; s1 += v1; s2 += v2; s3 += v3;
    q0 += v0 * v0; q1 += v1 * v1; q2 += v2 * v2; q3 += v3 * v3;
  }
  atomicAdd(&sums[c + 0], s0); atomicAdd(&sums[c + 1], s1);
  atomicAdd(&sums[c + 2], s2); atomicAdd(&sums[c + 3], s3);
  atomicAdd(&sums[F + c + 0], q0); atomicAdd(&sums[F + c + 1], q1);
  atomicAdd(&sums[F + c + 2], q2); atomicAdd(&sums[F + c + 3], q3);
}

// fp32-input variant (layer 2, small)
template <int CPT>
__global__ void bnstats_kernel(const float* __restrict__ x, float* __restrict__ sums,
                               int nrows, int F, int rowsPerBlock) {
  int tid = threadIdx.x;
  int r0 = blockIdx.x * rowsPerBlock;
  int rend = min(r0 + rowsPerBlock, nrows);
  float s[CPT], q[CPT];
#pragma unroll
  for (int k = 0; k < CPT; ++k) { s[k] = 0.f; q[k] = 0.f; }
  for (int r = r0; r < rend; ++r) {
    const float* row = x + (size_t)r * F;
#pragma unroll
    for (int k = 0; k < CPT; ++k) {
      float v = row[tid + k * blockDim.x];
      s[k] += v; q[k] += v * v;
    }
  }
#pragma unroll
  for (int k = 0; k < CPT; ++k) {
    atomicAdd(&sums[tid + k * blockDim.x], s[k]);
    atomicAdd(&sums[F + tid + k * blockDim.x], q[k]);
  }
}

__global__ void bnfinal_kernel(const float* __restrict__ sums, const float* __restrict__ g,
                               const float* __restrict__ be, float* __restrict__ ss, int F) {
  int c = blockIdx.x * blockDim.x + threadIdx.x;
  if (c < F) {
    float mu = sums[c] * (1.f / N_NODES);
    float var = sums[F + c] * (1.f / N_NODES) - mu * mu;
    float sc = g[c] * rsqrtf(var + BN_EPS);
    ss[c] = sc;
    ss[F + c] = be[c] - mu * sc;
  }
}

// BN apply + ELU, bf16 in-place (layer 1, feeds GEMM2)
__global__ void bnapply_bf16_kernel(unsigned short* __restrict__ x, const float* __restrict__ ss,
                                    int F, size_t total4) {
  size_t i = (size_t)blockIdx.x * blockDim.x + threadIdx.x;
  size_t stride = (size_t)gridDim.x * blockDim.x;
  for (; i < total4; i += stride) {
    int c = (int)((i * 4) & (size_t)(F - 1));
    ushort4 u = ((ushort4*)x)[i];
    float v0 = b2f(u.x) * ss[c + 0] + ss[F + c + 0];
    float v1 = b2f(u.y) * ss[c + 1] + ss[F + c + 1];
    float v2 = b2f(u.z) * ss[c + 2] + ss[F + c + 2];
    float v3 = b2f(u.w) * ss[c + 3] + ss[F + c + 3];
    v0 = v0 > 0.f ? v0 : expm1f(v0);
    v1 = v1 > 0.f ? v1 : expm1f(v1);
    v2 = v2 > 0.f ? v2 : expm1f(v2);
    v3 = v3 > 0.f ? v3 : expm1f(v3);
    u.x = f2bu(v0); u.y = f2bu(v1); u.z = f2bu(v2); u.w = f2bu(v3);
    ((ushort4*)x)[i] = u;
  }
}

// ---------------- gather layer 2: online softmax, chunk-4 double-buffered ----------------
#define G2_LOAD(i, rv, ev)                                                     \
  if ((i) < e) {                                                               \
    int ssrc = elist[(i)];                                                     \
    ev = leaky(as2[ssrc] + ad);                                                \
    rv = *(const unsigned*)(h2 + (size_t)ssrc * F2 + tid * 2);                 \
  }
#define G2_CONSUME(u, el)                                                      \
  {                                                                            \
    float w;                                                                   \
    if (el > m + RESCALE_THR) {                                                \
      float rr = __expf(m - el);                                               \
      z *= rr; a0 *= rr; a1 *= rr;                                             \
      m = el; w = 1.f;                                                         \
    } else {                                                                   \
      w = __expf(el - m);                                                      \
    }                                                                          \
    z += w;                                                                    \
    a0 += w * __uint_as_float(u << 16);                                        \
    a1 += w * __uint_as_float(u & 0xffff0000u);                                \
  }

__global__ __launch_bounds__(64) void gather2_kernel(const unsigned short* __restrict__ h2,
                                                     const float* __restrict__ as2,
                                                     const float* __restrict__ ad2,
                                                     const int* __restrict__ off,
                                                     const int* __restrict__ elist,
                                                     const float* __restrict__ b2,
                                                     float* __restrict__ out2) {
  int node = blockIdx.x;
  int tid = threadIdx.x;          // 64, 2 channels each
  const float ad = ad2[node];
  int s = off[node], e = off[node + 1];
  float m = leaky(as2[node] + ad);
  float z = 1.f;
  float a0, a1;
  {
    unsigned u = *(const unsigned*)(h2 + (size_t)node * F2 + tid * 2);
    a0 = __uint_as_float(u << 16); a1 = __uint_as_float(u & 0xffff0000u);
  }
  unsigned ra0 = 0, ra1 = 0, ra2 = 0, ra3 = 0;
  float ea0 = 0.f, ea1 = 0.f, ea2 = 0.f, ea3 = 0.f;
  G2_LOAD(s + 0, ra0, ea0)
  G2_LOAD(s + 1, ra1, ea1)
  G2_LOAD(s + 2, ra2, ea2)
  G2_LOAD(s + 3, ra3, ea3)
  for (int base = s; base < e; base += 4) {
    unsigned rb0 = 0, rb1 = 0, rb2 = 0, rb3 = 0;
    float eb0 = 0.f, eb1 = 0.f, eb2 = 0.f, eb3 = 0.f;
    int nb = base + 4;
    G2_LOAD(nb + 0, rb0, eb0)
    G2_LOAD(nb + 1, rb1, eb1)
    G2_LOAD(nb + 2, rb2, eb2)
    G2_LOAD(nb + 3, rb3, eb3)
    G2_CONSUME(ra0, ea0)
    if (base + 1 < e) G2_CONSUME(ra1, ea1)
    if (base + 2 < e) G2_CONSUME(ra2, ea2)
    if (base + 3 < e) G2_CONSUME(ra3, ea3)
    ra0 = rb0; ra1 = rb1; ra2 = rb2; ra3 = rb3;
    ea0 = eb0; ea1 = eb1; ea2 = eb2; ea3 = eb3;
  }
  float inv = 1.f / z;
  float2 o = make_float2(a0 * inv + b2[tid * 2 + 0], a1 * inv + b2[tid * 2 + 1]);
  *(float2*)(out2 + (size_t)node * F2 + tid * 2) = o;
}

// ---------------- classifier head (fused BN2 apply + ELU) ----------------
__global__ __launch_bounds__(64) void cls_kernel(const float* __restrict__ h,
                                                 const float* __restrict__ ss2,
                                                 const float* __restrict__ Wc1,
                                                 const float* __restrict__ bc1,
                                                 const float* __restrict__ Wc2,
                                                 const float* __restrict__ bc2,
                                                 float* __restrict__ out) {
  __shared__ float hl[128];
  int node = blockIdx.x;
  int tid = threadIdx.x;          // 64
  {
    float v = h[(size_t)node * F2 + tid] * ss2[tid] + ss2[F2 + tid];
    v = v > 0.f ? v : expm1f(v);
    hl[tid] = v;
    float v2 = h[(size_t)node * F2 + 64 + tid] * ss2[64 + tid] + ss2[F2 + 64 + tid];
    v2 = v2 > 0.f ? v2 : expm1f(v2);
    hl[tid + 64] = v2;
  }
  __syncthreads();
  float acc = bc1[tid];
#pragma unroll
  for (int k = 0; k < 128; ++k) acc += hl[k] * Wc1[k * 64 + tid];
  acc = fmaxf(acc, 0.f);
  float2 w = *(const float2*)(Wc2 + tid * 2);
  float o0 = acc * w.x, o1 = acc * w.y;
  for (int sh = 32; sh >= 1; sh >>= 1) {
    o0 += __shfl_down(o0, sh, 64);
    o1 += __shfl_down(o1, sh, 64);
  }
  if (tid == 0) {
    out[node * 2 + 0] = o0 + bc2[0];
    out[node * 2 + 1] = o1 + bc2[1];
  }
}

extern "C" void kernel_launch(void* const* d_in, const int* in_sizes, int n_in,
                              void* d_out, int out_size, void* d_ws, size_t ws_size,
                              hipStream_t stream) {
  const float* x        = (const float*)d_in[0];
  const int*   ei_raw   = (const int*)d_in[1];
  const float* W1       = (const float*)d_in[2];
  const float* att_src1 = (const float*)d_in[3];
  const float* att_dst1 = (const float*)d_in[4];
  const float* b1       = (const float*)d_in[5];
  const float* W2       = (const float*)d_in[6];
  const float* att_src2 = (const float*)d_in[7];
  const float* att_dst2 = (const float*)d_in[8];
  const float* b2       = (const float*)d_in[9];
  const float* g1       = (const float*)d_in[10];
  const float* be1      = (const float*)d_in[11];
  const float* g2       = (const float*)d_in[12];
  const float* be2      = (const float*)d_in[13];
  const float* Wc1      = (const float*)d_in[14];
  const float* bc1      = (const float*)d_in[15];
  const float* Wc2      = (const float*)d_in[16];
  const float* bc2      = (const float*)d_in[17];
  float* out = (float*)d_out;

  char* ws = (char*)d_ws;
  size_t o = 0;
  unsigned short* h1b   = (unsigned short*)(ws + o); o += (size_t)N_NODES * F1 * 2;  // 40.96 MB
  unsigned short* out1b = (unsigned short*)(ws + o); o += (size_t)N_NODES * F1 * 2;  // 40.96 MB
  unsigned short* xb    = (unsigned short*)(ws + o); o += (size_t)N_NODES * DIN * 2; // 30.72 MB
  unsigned short* h2b   = (unsigned short*)(ws + o); o += (size_t)N_NODES * F2 * 2;  // 5.12 MB
  float* out2  = (float*)(ws + o); o += (size_t)N_NODES * F2 * 4;                    // 10.24 MB
  float* as1   = (float*)(ws + o); o += (size_t)N_NODES * H1 * 4;
  float* ad1   = (float*)(ws + o); o += (size_t)N_NODES * H1 * 4;
  float* as2   = (float*)(ws + o); o += (size_t)N_NODES * 4;
  float* ad2   = (float*)(ws + o); o += (size_t)N_NODES * 4;
  char*  zbase = ws + o;
  float* bnsum1 = (float*)(ws + o); o += F1 * 2 * 4;
  float* bnsum2 = (float*)(ws + o); o += F2 * 2 * 4;
  int*   deg    = (int*)(ws + o); o += (size_t)N_NODES * 4;
  size_t zbytes = (size_t)((ws + o) - zbase);
  int*   offv   = (int*)(ws + o); o += (size_t)(N_NODES + 4) * 4;
  int*   cursor = (int*)(ws + o); o += (size_t)N_NODES * 4;
  int*   elist  = (int*)(ws + o); o += (size_t)N_EDGES * 4;
  float* ss1    = (float*)(ws + o); o += F1 * 2 * 4;
  float* ss2    = (float*)(ws + o); o += F2 * 2 * 4;
  int*   ei32   = (int*)(ws + o); o += (size_t)2 * N_EDGES * 4;
  unsigned short* W1T = (unsigned short*)(ws + o); o += (size_t)F1 * DIN * 2;
  unsigned short* W2T = (unsigned short*)(ws + o); o += (size_t)F2 * F1 * 2;
  (void)ws_size; (void)in_sizes; (void)n_in; (void)out_size;

  hipMemsetAsync((void*)zbase, 0, zbytes, stream);

  // input conversions
  f2b_kernel<<<2048, 256, 0, stream>>>(x, xb, (size_t)N_NODES * DIN / 4);
  {
    dim3 g1d(F1 / 32, DIN / 32);
    transpose_b_kernel<<<g1d, 256, 0, stream>>>(W1, W1T, DIN, F1);
    dim3 g2d(F2 / 32, F1 / 32);
    transpose_b_kernel<<<g2d, 256, 0, stream>>>(W2, W2T, F1, F2);
  }

  // CSR build
  repack_hist_kernel<<<(2 * N_EDGES + 255) / 256, 256, 0, stream>>>(ei_raw, ei32, deg);
  scan_kernel<<<1, 1024, 0, stream>>>(deg, offv, cursor);
  scatter_kernel<<<(N_EDGES + 255) / 256, 256, 0, stream>>>(ei32, cursor, elist);

  // layer 1: h1 = x @ W1 (bf16 MFMA, fused att logits, XCD panel-affinity swizzle)
  {
    int panels = (N_NODES + GBM - 1) / GBM;          // 157
    int grid1 = ((panels + 7) / 8) * 64;             // 1280
    mfma_gemm_att_kernel<H1, 1><<<grid1, 256, 0, stream>>>(
        xb, W1T, h1b, att_src1, att_dst1, as1, ad1, N_NODES, F1, DIN);
  }
  gather1_kernel<<<N_NODES, 128, 0, stream>>>(h1b, as1, ad1, offv, elist, b1, out1b);
  {
    int rows = 79;
    int grid = (N_NODES + rows - 1) / rows;
    bnstats_bf16_kernel<<<grid, 256, 0, stream>>>(out1b, bnsum1, N_NODES, F1, rows);
  }
  bnfinal_kernel<<<(F1 + 255) / 256, 256, 0, stream>>>(bnsum1, g1, be1, ss1, F1);
  bnapply_bf16_kernel<<<2048, 256, 0, stream>>>(out1b, ss1, F1, (size_t)N_NODES * F1 / 4);

  // layer 2: h2 = out1b @ W2 (bf16 MFMA, fused att logits)
  {
    dim3 grid(F2 / GBN, (N_NODES + GBM - 1) / GBM);
    mfma_gemm_att_kernel<1, 0><<<grid, 256, 0, stream>>>(
        out1b, W2T, h2b, att_src2, att_dst2, as2, ad2, N_NODES, F2, F1);
  }
  gather2_kernel<<<N_NODES, 64, 0, stream>>>(h2b, as2, ad2, offv, elist, b2, out2);
  {
    int rows = 79;
    int grid = (N_NODES + rows - 1) / rows;
    bnstats_kernel<1><<<grid, 128, 0, stream>>>(out2, bnsum2, N_NODES, F2, rows);
  }
  bnfinal_kernel<<<1, F2, 0, stream>>>(bnsum2, g2, be2, ss2, F2);

  // classifier (BN2 apply + ELU fused)
  cls_kernel<<<N_NODES, 64, 0, stream>>>(out2, ss2, Wc1, bc1, Wc2, bc2, out);
}